// Round 1
// baseline (926.952 us; speedup 1.0000x reference)
//
#include <hip/hip_runtime.h>
#include <math.h>

#define Bn 256
#define Cn 3
#define Hn 224
#define Wn 224
#define CROPD 190

static constexpr long long NTOT = (long long)Bn * Cn * Hn * Wn;

__device__ __forceinline__ float keys_cubic(float x) {
    // JAX _fill_keys_cubic_kernel (a = -0.5)
    if (x < 1.f) return ((1.5f * x - 2.5f) * x) * x + 1.f;
    if (x < 2.f) return ((-0.5f * x + 2.5f) * x - 4.f) * x + 2.f;
    return 0.f;
}

// params[b*12 + {0..7:homography coeffs, 8:cos, 9:sin, 10:brightness factor, 11:flip}]
__global__ void params_kernel(const int* __restrict__ ep_raw,
                              const int* __restrict__ angles,
                              const float* __restrict__ brightness,
                              const int* __restrict__ flip_mask,
                              float* __restrict__ params) {
    int b = blockIdx.x * blockDim.x + threadIdx.x;
    if (b >= Bn) return;
    const double offx[4] = {0.0, 195.0, 195.0, 0.0};
    const double offy[4] = {0.0, 0.0, 195.0, 195.0};
    const double sxc[4]  = {0.0, 223.0, 223.0, 0.0};
    const double syc[4]  = {0.0, 0.0, 223.0, 223.0};
    double M[8][9];
    for (int i = 0; i < 4; i++) {
        double ex = (double)ep_raw[b * 8 + i * 2 + 0] + offx[i];
        double ey = (double)ep_raw[b * 8 + i * 2 + 1] + offy[i];
        double sx = sxc[i], sy = syc[i];
        M[i][0] = ex; M[i][1] = ey; M[i][2] = 1.0;
        M[i][3] = 0.0; M[i][4] = 0.0; M[i][5] = 0.0;
        M[i][6] = -sx * ex; M[i][7] = -sx * ey; M[i][8] = sx;
        M[i + 4][0] = 0.0; M[i + 4][1] = 0.0; M[i + 4][2] = 0.0;
        M[i + 4][3] = ex; M[i + 4][4] = ey; M[i + 4][5] = 1.0;
        M[i + 4][6] = -sy * ex; M[i + 4][7] = -sy * ey; M[i + 4][8] = sy;
    }
    // Gaussian elimination with partial pivoting (f64)
    for (int k = 0; k < 8; k++) {
        int piv = k; double best = fabs(M[k][k]);
        for (int r = k + 1; r < 8; r++) {
            double v = fabs(M[r][k]);
            if (v > best) { best = v; piv = r; }
        }
        if (piv != k) {
            for (int j = 0; j < 9; j++) { double t = M[k][j]; M[k][j] = M[piv][j]; M[piv][j] = t; }
        }
        double inv = 1.0 / M[k][k];
        for (int r = k + 1; r < 8; r++) {
            double f = M[r][k] * inv;
            M[r][k] = 0.0;
            for (int j = k + 1; j < 9; j++) M[r][j] -= f * M[k][j];
        }
    }
    double sol[8];
    for (int k = 7; k >= 0; k--) {
        double s = M[k][8];
        for (int j = k + 1; j < 8; j++) s -= M[k][j] * sol[j];
        sol[k] = s / M[k][k];
    }
    float* p = params + b * 12;
    for (int j = 0; j < 8; j++) p[j] = (float)sol[j];
    double th = ((double)angles[b] - 16.0) * (M_PI / 180.0);
    p[8]  = (float)cos(th);
    p[9]  = (float)sin(th);
    p[10] = 0.85f + 0.3f * brightness[b];
    p[11] = (flip_mask[b] > 0) ? 1.0f : 0.0f;
}

// Stage 1: flip + noise + brightness + perspective bilinear -> P
__global__ void persp_kernel(const float* __restrict__ xin,
                             const float* __restrict__ noise,
                             const float* __restrict__ params,
                             float* __restrict__ outP) {
    unsigned int n = blockIdx.x * blockDim.x + threadIdx.x;
    if (n >= (unsigned int)NTOT) return;
    unsigned int xi_ = n % Wn;
    unsigned int t = n / Wn;
    unsigned int y = t % Hn; t /= Hn;
    unsigned int c = t % Cn;
    unsigned int b = t / Cn;
    const float* p = params + b * 12;
    float Xg = (float)xi_ + 0.5f, Yg = (float)y + 0.5f;
    float den = p[6] * Xg + p[7] * Yg + 1.0f;
    float sx = (p[0] * Xg + p[1] * Yg + p[2]) / den - 0.5f;
    float sy = (p[3] * Xg + p[4] * Yg + p[5]) / den - 0.5f;
    float fx0 = floorf(sx), fy0 = floorf(sy);
    float wx = sx - fx0, wy = sy - fy0;
    int x0 = (int)fx0, y0 = (int)fy0;
    float bf = p[10];
    bool flip = p[11] > 0.5f;
    const size_t base = ((size_t)b * Cn + c) * (size_t)(Hn * Wn);
    const float* xb = xin + base;
    const float* nb = noise + base;
    float acc = 0.f;
#pragma unroll
    for (int dy = 0; dy < 2; dy++) {
        int yy = y0 + dy;
        if (yy < 0 || yy >= Hn) continue;
        float wyv = dy ? wy : 1.f - wy;
#pragma unroll
        for (int dx = 0; dx < 2; dx++) {
            int xx = x0 + dx;
            if (xx < 0 || xx >= Wn) continue;
            float wxv = dx ? wx : 1.f - wx;
            int xs = flip ? (Wn - 1 - xx) : xx;
            float v = (xb[yy * Wn + xs] + 0.625f * nb[yy * Wn + xx]) * bf;
            acc += v * (wxv * wyv);
        }
    }
    outP[n] = acc;
}

// Stage 2: rotation bilinear P -> R
__global__ void rotate_kernel(const float* __restrict__ P,
                              const float* __restrict__ params,
                              float* __restrict__ outR) {
    unsigned int n = blockIdx.x * blockDim.x + threadIdx.x;
    if (n >= (unsigned int)NTOT) return;
    unsigned int xi_ = n % Wn;
    unsigned int t = n / Wn;
    unsigned int y = t % Hn; t /= Hn;
    unsigned int c = t % Cn;
    unsigned int b = t / Cn;
    const float* p = params + b * 12;
    float cs = p[8], sn = p[9];
    const float cx = (Wn - 1) * 0.5f;   // 111.5
    float dx = (float)xi_ - cx;
    float dy = (float)y - cx;
    float rx = cs * dx + sn * dy + cx;
    float ry = -sn * dx + cs * dy + cx;
    float fx0 = floorf(rx), fy0 = floorf(ry);
    float wx = rx - fx0, wy = ry - fy0;
    int x0 = (int)fx0, y0 = (int)fy0;
    const size_t base = ((size_t)b * Cn + c) * (size_t)(Hn * Wn);
    const float* Pb = P + base;
    float acc = 0.f;
#pragma unroll
    for (int ddy = 0; ddy < 2; ddy++) {
        int yy = y0 + ddy;
        if (yy < 0 || yy >= Hn) continue;
        float wyv = ddy ? wy : 1.f - wy;
#pragma unroll
        for (int ddx = 0; ddx < 2; ddx++) {
            int xx = x0 + ddx;
            if (xx < 0 || xx >= Wn) continue;
            float wxv = ddx ? wx : 1.f - wx;
            acc += Pb[yy * Wn + xx] * (wxv * wyv);
        }
    }
    outR[n] = acc;
}

// Stage 3: crop (dynamic slice) + bicubic resize 190->224 (jax.image.resize semantics)
__global__ void resize_kernel(const float* __restrict__ R,
                              const int* __restrict__ crop_ij,
                              float* __restrict__ out) {
    unsigned int n = blockIdx.x * blockDim.x + threadIdx.x;
    if (n >= (unsigned int)NTOT) return;
    unsigned int ox = n % Wn;
    unsigned int t = n / Wn;
    unsigned int oy = t % Hn; t /= Hn;
    unsigned int c = t % Cn;
    unsigned int b = t / Cn;
    const float scale = (float)CROPD / (float)Wn;   // inv_scale = 190/224 (upscale -> no antialias widening)
    float sfy = ((float)oy + 0.5f) * scale - 0.5f;
    float sfx = ((float)ox + 0.5f) * scale - 0.5f;
    int iy0 = (int)floorf(sfy);
    int ix0 = (int)floorf(sfx);
    float wy[4], wx[4];
    float sumy = 0.f, sumx = 0.f;
#pragma unroll
    for (int k = 0; k < 4; k++) {
        int i = iy0 - 1 + k;
        float w = (i >= 0 && i < CROPD) ? keys_cubic(fabsf(sfy - (float)i)) : 0.f;
        wy[k] = w; sumy += w;
    }
#pragma unroll
    for (int k = 0; k < 4; k++) {
        int i = ix0 - 1 + k;
        float w = (i >= 0 && i < CROPD) ? keys_cubic(fabsf(sfx - (float)i)) : 0.f;
        wx[k] = w; sumx += w;
    }
    float norm = 1.f / (sumy * sumx);   // per-axis renormalization (edge taps excluded)
    int ci = crop_ij[b * 2 + 0];
    int cj = crop_ij[b * 2 + 1];
    const size_t base = ((size_t)b * Cn + c) * (size_t)(Hn * Wn);
    const float* Rb = R + base;
    float acc = 0.f;
#pragma unroll
    for (int ky = 0; ky < 4; ky++) {
        int iy = iy0 - 1 + ky;
        if (iy < 0 || iy >= CROPD) continue;
        int gy = iy + ci;
        float rowa = 0.f;
#pragma unroll
        for (int kx = 0; kx < 4; kx++) {
            int ix = ix0 - 1 + kx;
            if (ix < 0 || ix >= CROPD) continue;
            rowa += wx[kx] * Rb[gy * Wn + ix + cj];
        }
        acc += wy[ky] * rowa;
    }
    out[n] = acc * norm;
}

extern "C" void kernel_launch(void* const* d_in, const int* in_sizes, int n_in,
                              void* d_out, int out_size, void* d_ws, size_t ws_size,
                              hipStream_t stream) {
    const float* x          = (const float*)d_in[0];
    const float* noise      = (const float*)d_in[1];
    const float* brightness = (const float*)d_in[2];
    const int*   flip_mask  = (const int*)d_in[3];
    const int*   ep_raw     = (const int*)d_in[4];
    const int*   angles     = (const int*)d_in[5];
    const int*   crop_ij    = (const int*)d_in[6];
    float* out = (float*)d_out;

    float* params = (float*)d_ws;                       // 256*12 floats
    float* Rbuf   = (float*)((char*)d_ws + 12288);      // B*C*H*W floats

    int blocks = (int)((NTOT + 255) / 256);

    params_kernel<<<1, 256, 0, stream>>>(ep_raw, angles, brightness, flip_mask, params);
    // P staged in d_out (fully overwritten again by resize_kernel)
    persp_kernel<<<blocks, 256, 0, stream>>>(x, noise, params, out);
    rotate_kernel<<<blocks, 256, 0, stream>>>(out, params, Rbuf);
    resize_kernel<<<blocks, 256, 0, stream>>>(Rbuf, crop_ij, out);
}

// Round 2
// 699.848 us; speedup vs baseline: 1.3245x; 1.3245x over previous
//
#include <hip/hip_runtime.h>
#include <math.h>

#define Bn 256
#define Cn 3
#define Hn 224
#define Wn 224
#define CROPD 190

static constexpr long long NTOT = (long long)Bn * Cn * Hn * Wn;   // 38,535,168
static constexpr int PLANE = Hn * Wn;                              // 50176
static constexpr int TPLANE = CROPD * Wn;                          // 42560

// Bicubic weight tables (identical for x and y axis: 190 -> 224, Keys a=-0.5,
// per-axis renormalized with out-of-range taps excluded). Filled every launch
// by params_kernel (deterministic), consumed by hpass/vpass.
__device__ int    g_i0[Wn];
__device__ float4 g_wt[Wn];

__device__ __forceinline__ float keys_cubic(float x) {
    if (x < 1.f) return ((1.5f * x - 2.5f) * x) * x + 1.f;
    if (x < 2.f) return ((-0.5f * x + 2.5f) * x - 4.f) * x + 2.f;
    return 0.f;
}

// params[b*12 + {0..7: homography, 8: cos, 9: sin, 10: brightness, 11: flip}]
__global__ void params_kernel(const int* __restrict__ ep_raw,
                              const int* __restrict__ angles,
                              const float* __restrict__ brightness,
                              const int* __restrict__ flip_mask,
                              float* __restrict__ params) {
    int b = threadIdx.x;

    // ---- bicubic weight table (threads 0..223) ----
    if (b < Wn) {
        float sf = ((float)b + 0.5f) * ((float)CROPD / (float)Wn) - 0.5f;
        int i0 = (int)floorf(sf);
        float w[4]; float s = 0.f;
#pragma unroll
        for (int k = 0; k < 4; k++) {
            int idx = i0 - 1 + k;
            float wk = (idx >= 0 && idx < CROPD) ? keys_cubic(fabsf(sf - (float)idx)) : 0.f;
            w[k] = wk; s += wk;
        }
        float inv = 1.f / s;
        g_i0[b] = i0;
        g_wt[b] = make_float4(w[0] * inv, w[1] * inv, w[2] * inv, w[3] * inv);
    }

    if (b >= Bn) return;

    const double offx[4] = {0.0, 195.0, 195.0, 0.0};
    const double offy[4] = {0.0, 0.0, 195.0, 195.0};
    const double sxc[4]  = {0.0, 223.0, 223.0, 0.0};
    const double syc[4]  = {0.0, 0.0, 223.0, 223.0};
    double M[8][9];
    for (int i = 0; i < 4; i++) {
        double ex = (double)ep_raw[b * 8 + i * 2 + 0] + offx[i];
        double ey = (double)ep_raw[b * 8 + i * 2 + 1] + offy[i];
        double sx = sxc[i], sy = syc[i];
        M[i][0] = ex; M[i][1] = ey; M[i][2] = 1.0;
        M[i][3] = 0.0; M[i][4] = 0.0; M[i][5] = 0.0;
        M[i][6] = -sx * ex; M[i][7] = -sx * ey; M[i][8] = sx;
        M[i + 4][0] = 0.0; M[i + 4][1] = 0.0; M[i + 4][2] = 0.0;
        M[i + 4][3] = ex; M[i + 4][4] = ey; M[i + 4][5] = 1.0;
        M[i + 4][6] = -sy * ex; M[i + 4][7] = -sy * ey; M[i + 4][8] = sy;
    }
    for (int k = 0; k < 8; k++) {
        int piv = k; double best = fabs(M[k][k]);
        for (int r = k + 1; r < 8; r++) {
            double v = fabs(M[r][k]);
            if (v > best) { best = v; piv = r; }
        }
        if (piv != k)
            for (int j = 0; j < 9; j++) { double t = M[k][j]; M[k][j] = M[piv][j]; M[piv][j] = t; }
        double inv = 1.0 / M[k][k];
        for (int r = k + 1; r < 8; r++) {
            double f = M[r][k] * inv;
            M[r][k] = 0.0;
            for (int j = k + 1; j < 9; j++) M[r][j] -= f * M[k][j];
        }
    }
    double sol[8];
    for (int k = 7; k >= 0; k--) {
        double s = M[k][8];
        for (int j = k + 1; j < 8; j++) s -= M[k][j] * sol[j];
        sol[k] = s / M[k][k];
    }
    float* p = params + b * 12;
    for (int j = 0; j < 8; j++) p[j] = (float)sol[j];
    double th = ((double)angles[b] - 16.0) * (M_PI / 180.0);
    p[8]  = (float)cos(th);
    p[9]  = (float)sin(th);
    p[10] = 0.85f + 0.3f * brightness[b];
    p[11] = (flip_mask[b] > 0) ? 1.0f : 0.0f;
}

// Stage 1: flip + noise + brightness + perspective bilinear. 4 outputs/thread.
__global__ void persp_kernel(const float* __restrict__ xin,
                             const float* __restrict__ noise,
                             const float* __restrict__ params,
                             float* __restrict__ outP) {
    unsigned int n = blockIdx.x * blockDim.x + threadIdx.x;   // quad index
    unsigned int qx = n % (Wn / 4);
    unsigned int t = n / (Wn / 4);
    unsigned int y = t % Hn; t /= Hn;
    unsigned int c = t % Cn;
    unsigned int b = t / Cn;
    const float* p = params + b * 12;
    float a0 = p[0], a1 = p[1], a2 = p[2], a3 = p[3], a4 = p[4], a5 = p[5];
    float g = p[6], h = p[7], bf = p[10];
    bool flip = p[11] > 0.5f;
    float Yg = (float)y + 0.5f;
    const size_t base = ((size_t)b * Cn + c) * (size_t)PLANE;
    const float* xb = xin + base;
    const float* nb = noise + base;
    float racc[4];
#pragma unroll
    for (int o = 0; o < 4; o++) {
        float Xg = (float)(qx * 4 + o) + 0.5f;
        float den = g * Xg + h * Yg + 1.0f;
        float rden = 1.0f / den;
        float sx = (a0 * Xg + a1 * Yg + a2) * rden - 0.5f;
        float sy = (a3 * Xg + a4 * Yg + a5) * rden - 0.5f;
        float fx0 = floorf(sx), fy0 = floorf(sy);
        float wx = sx - fx0, wy = sy - fy0;
        int x0 = (int)fx0, y0 = (int)fy0;
        float acc = 0.f;
#pragma unroll
        for (int dy = 0; dy < 2; dy++) {
            int yy = y0 + dy;
            float wyv = dy ? wy : 1.f - wy;
            bool yv = (unsigned)yy < (unsigned)Hn;
            int yc = min(max(yy, 0), Hn - 1);
#pragma unroll
            for (int dx = 0; dx < 2; dx++) {
                int xx = x0 + dx;
                float wxv = dx ? wx : 1.f - wx;
                bool v = yv && ((unsigned)xx < (unsigned)Wn);
                int xc = min(max(xx, 0), Wn - 1);
                float wgt = v ? wxv * wyv : 0.f;
                int xs = flip ? (Wn - 1 - xc) : xc;
                acc += (xb[yc * Wn + xs] + 0.625f * nb[yc * Wn + xc]) * wgt;
            }
        }
        racc[o] = acc * bf;
    }
    float4 r4 = make_float4(racc[0], racc[1], racc[2], racc[3]);
    *reinterpret_cast<float4*>(outP + ((size_t)b * Cn + c) * PLANE + y * Wn + qx * 4) = r4;
}

// Stage 2: rotation bilinear. 4 outputs/thread.
__global__ void rotate_kernel(const float* __restrict__ P,
                              const float* __restrict__ params,
                              float* __restrict__ outR) {
    unsigned int n = blockIdx.x * blockDim.x + threadIdx.x;
    unsigned int qx = n % (Wn / 4);
    unsigned int t = n / (Wn / 4);
    unsigned int y = t % Hn; t /= Hn;
    unsigned int c = t % Cn;
    unsigned int b = t / Cn;
    const float* p = params + b * 12;
    float cs = p[8], sn = p[9];
    const float cx = (Wn - 1) * 0.5f;
    float dy = (float)y - cx;
    float dx0 = (float)(qx * 4) - cx;
    float rx0 = cs * dx0 + sn * dy + cx;
    float ry0 = -sn * dx0 + cs * dy + cx;
    const size_t base = ((size_t)b * Cn + c) * (size_t)PLANE;
    const float* Pb = P + base;
    float racc[4];
#pragma unroll
    for (int o = 0; o < 4; o++) {
        float rx = rx0 + cs * (float)o;
        float ry = ry0 - sn * (float)o;
        float fx0 = floorf(rx), fy0 = floorf(ry);
        float wx = rx - fx0, wy = ry - fy0;
        int x0 = (int)fx0, y0 = (int)fy0;
        float acc = 0.f;
#pragma unroll
        for (int ddy = 0; ddy < 2; ddy++) {
            int yy = y0 + ddy;
            float wyv = ddy ? wy : 1.f - wy;
            bool yv = (unsigned)yy < (unsigned)Hn;
            int yc = min(max(yy, 0), Hn - 1);
#pragma unroll
            for (int ddx = 0; ddx < 2; ddx++) {
                int xx = x0 + ddx;
                float wxv = ddx ? wx : 1.f - wx;
                bool v = yv && ((unsigned)xx < (unsigned)Wn);
                int xc = min(max(xx, 0), Wn - 1);
                float wgt = v ? wxv * wyv : 0.f;
                acc += Pb[yc * Wn + xc] * wgt;
            }
        }
        racc[o] = acc;
    }
    float4 r4 = make_float4(racc[0], racc[1], racc[2], racc[3]);
    *reinterpret_cast<float4*>(outR + base + y * Wn + qx * 4) = r4;
}

// Stage 3a: crop + horizontal bicubic 190->224. One output/thread.
// T[b][c][y<190][ox<224] = sum_k wt[ox].k * R[b][c][y+ci][cj + clamp(i0-1+k)]
__global__ void hpass_kernel(const float* __restrict__ R,
                             const int* __restrict__ crop_ij,
                             float* __restrict__ T) {
    unsigned int n = blockIdx.x * blockDim.x + threadIdx.x;
    unsigned int ox = n % Wn;
    unsigned int t = n / Wn;
    unsigned int y = t % CROPD;
    unsigned int p = t / CROPD;          // p = b*3+c
    unsigned int b = p / Cn;
    int ci = crop_ij[b * 2 + 0];
    int cj = crop_ij[b * 2 + 1];
    float4 w = g_wt[ox];
    int i0 = g_i0[ox];
    const float* Rrow = R + (size_t)p * PLANE + (size_t)(y + ci) * Wn + cj;
    float wk[4] = {w.x, w.y, w.z, w.w};
    float acc = 0.f;
#pragma unroll
    for (int k = 0; k < 4; k++) {
        int ix = min(max(i0 - 1 + k, 0), CROPD - 1);
        acc += wk[k] * Rrow[ix];
    }
    T[(size_t)p * TPLANE + y * Wn + ox] = acc;
}

// Stage 3b: vertical bicubic 190->224. 4 outputs/thread (float4).
__global__ void vpass_kernel(const float* __restrict__ T,
                             float* __restrict__ out) {
    unsigned int n = blockIdx.x * blockDim.x + threadIdx.x;
    unsigned int qx = n % (Wn / 4);
    unsigned int t = n / (Wn / 4);
    unsigned int oy = t % Hn;
    unsigned int p = t / Hn;             // b*3+c
    float4 w = g_wt[oy];
    int i0 = g_i0[oy];
    const float* Tp = T + (size_t)p * TPLANE;
    float wk[4] = {w.x, w.y, w.z, w.w};
    float4 acc = make_float4(0.f, 0.f, 0.f, 0.f);
#pragma unroll
    for (int k = 0; k < 4; k++) {
        int r = min(max(i0 - 1 + k, 0), CROPD - 1);
        float4 v = *reinterpret_cast<const float4*>(Tp + (size_t)r * Wn + qx * 4);
        acc.x += wk[k] * v.x;
        acc.y += wk[k] * v.y;
        acc.z += wk[k] * v.z;
        acc.w += wk[k] * v.w;
    }
    *reinterpret_cast<float4*>(out + (size_t)p * PLANE + oy * Wn + qx * 4) = acc;
}

extern "C" void kernel_launch(void* const* d_in, const int* in_sizes, int n_in,
                              void* d_out, int out_size, void* d_ws, size_t ws_size,
                              hipStream_t stream) {
    const float* x          = (const float*)d_in[0];
    const float* noise      = (const float*)d_in[1];
    const float* brightness = (const float*)d_in[2];
    const int*   flip_mask  = (const int*)d_in[3];
    const int*   ep_raw     = (const int*)d_in[4];
    const int*   angles     = (const int*)d_in[5];
    const int*   crop_ij    = (const int*)d_in[6];
    float* out = (float*)d_out;

    float* params = (float*)d_ws;                      // 256*12 floats
    float* Pbuf   = (float*)((char*)d_ws + 12288);     // persp out (B*C*H*W f32)
    float* Tbuf   = Pbuf;                              // H-pass out overwrites dead P (smaller)
    float* Rbuf   = out;                               // rotate out staged in d_out

    int quadBlocks = (int)((NTOT / 4) / 256);          // 37632, exact
    int hBlocks    = (int)(((long long)Bn * Cn * CROPD * Wn) / 256);  // 127680, exact

    params_kernel<<<1, 256, 0, stream>>>(ep_raw, angles, brightness, flip_mask, params);
    persp_kernel<<<quadBlocks, 256, 0, stream>>>(x, noise, params, Pbuf);
    rotate_kernel<<<quadBlocks, 256, 0, stream>>>(Pbuf, params, Rbuf);
    hpass_kernel<<<hBlocks, 256, 0, stream>>>(Rbuf, crop_ij, Tbuf);
    vpass_kernel<<<quadBlocks, 256, 0, stream>>>(Tbuf, out);
}

// Round 3
// 523.483 us; speedup vs baseline: 1.7707x; 1.3369x over previous
//
#include <hip/hip_runtime.h>
#include <math.h>

#define Bn 256
#define Cn 3
#define Hn 224
#define Wn 224
#define CROPD 190

static constexpr long long NTOT = (long long)Bn * Cn * Hn * Wn;   // 38,535,168
static constexpr int PLANE = Hn * Wn;                              // 50176
static constexpr int TPLANE = CROPD * Wn;                          // 42560

// LDS source-tile geometry for the gather kernels
#define TILE 32            // output tile is 32x32
#define TH 64              // max staged source rows
#define TW 64              // max staged source cols
#define TSTRIDE 65         // +1 pad

// Bicubic weight tables (shared by x and y axis: 190 -> 224, Keys a=-0.5,
// per-axis renormalized, out-of-range taps excluded).
__device__ int    g_i0[Wn];
__device__ float4 g_wt[Wn];

__device__ __forceinline__ float keys_cubic(float x) {
    if (x < 1.f) return ((1.5f * x - 2.5f) * x) * x + 1.f;
    if (x < 2.f) return ((-0.5f * x + 2.5f) * x - 4.f) * x + 2.f;
    return 0.f;
}

// params[b*12 + {0..7: homography, 8: cos, 9: sin, 10: brightness, 11: flip}]
__global__ void params_kernel(const int* __restrict__ ep_raw,
                              const int* __restrict__ angles,
                              const float* __restrict__ brightness,
                              const int* __restrict__ flip_mask,
                              float* __restrict__ params) {
    int b = threadIdx.x;

    if (b < Wn) {
        float sf = ((float)b + 0.5f) * ((float)CROPD / (float)Wn) - 0.5f;
        int i0 = (int)floorf(sf);
        float w[4]; float s = 0.f;
#pragma unroll
        for (int k = 0; k < 4; k++) {
            int idx = i0 - 1 + k;
            float wk = (idx >= 0 && idx < CROPD) ? keys_cubic(fabsf(sf - (float)idx)) : 0.f;
            w[k] = wk; s += wk;
        }
        float inv = 1.f / s;
        g_i0[b] = i0;
        g_wt[b] = make_float4(w[0] * inv, w[1] * inv, w[2] * inv, w[3] * inv);
    }

    if (b >= Bn) return;

    const double offx[4] = {0.0, 195.0, 195.0, 0.0};
    const double offy[4] = {0.0, 0.0, 195.0, 195.0};
    const double sxc[4]  = {0.0, 223.0, 223.0, 0.0};
    const double syc[4]  = {0.0, 0.0, 223.0, 223.0};
    double M[8][9];
    for (int i = 0; i < 4; i++) {
        double ex = (double)ep_raw[b * 8 + i * 2 + 0] + offx[i];
        double ey = (double)ep_raw[b * 8 + i * 2 + 1] + offy[i];
        double sx = sxc[i], sy = syc[i];
        M[i][0] = ex; M[i][1] = ey; M[i][2] = 1.0;
        M[i][3] = 0.0; M[i][4] = 0.0; M[i][5] = 0.0;
        M[i][6] = -sx * ex; M[i][7] = -sx * ey; M[i][8] = sx;
        M[i + 4][0] = 0.0; M[i + 4][1] = 0.0; M[i + 4][2] = 0.0;
        M[i + 4][3] = ex; M[i + 4][4] = ey; M[i + 4][5] = 1.0;
        M[i + 4][6] = -sy * ex; M[i + 4][7] = -sy * ey; M[i + 4][8] = sy;
    }
    for (int k = 0; k < 8; k++) {
        int piv = k; double best = fabs(M[k][k]);
        for (int r = k + 1; r < 8; r++) {
            double v = fabs(M[r][k]);
            if (v > best) { best = v; piv = r; }
        }
        if (piv != k)
            for (int j = 0; j < 9; j++) { double t = M[k][j]; M[k][j] = M[piv][j]; M[piv][j] = t; }
        double inv = 1.0 / M[k][k];
        for (int r = k + 1; r < 8; r++) {
            double f = M[r][k] * inv;
            M[r][k] = 0.0;
            for (int j = k + 1; j < 9; j++) M[r][j] -= f * M[k][j];
        }
    }
    double sol[8];
    for (int k = 7; k >= 0; k--) {
        double s = M[k][8];
        for (int j = k + 1; j < 8; j++) s -= M[k][j] * sol[j];
        sol[k] = s / M[k][k];
    }
    float* p = params + b * 12;
    for (int j = 0; j < 8; j++) p[j] = (float)sol[j];
    double th = ((double)angles[b] - 16.0) * (M_PI / 180.0);
    p[8]  = (float)cos(th);
    p[9]  = (float)sin(th);
    p[10] = 0.85f + 0.3f * brightness[b];
    p[11] = (flip_mask[b] > 0) ? 1.0f : 0.0f;
}

// Stage 1: flip + noise + brightness + perspective bilinear, LDS-tiled.
// grid: 768 planes * 49 tiles; block 256 threads -> 32x32 outputs (4/thread).
__global__ __launch_bounds__(256) void persp_kernel(const float* __restrict__ xin,
                                                    const float* __restrict__ noise,
                                                    const float* __restrict__ params,
                                                    float* __restrict__ outP) {
    __shared__ float lds[TH * TSTRIDE];
    int bi = blockIdx.x;
    int p = bi / 49;
    int t = bi % 49;
    int ty = (t / 7) * TILE;
    int tx = (t % 7) * TILE;
    int b = p / Cn;
    const float* prm = params + b * 12;
    float a0 = prm[0], a1 = prm[1], a2 = prm[2];
    float a3 = prm[3], a4 = prm[4], a5 = prm[5];
    float g = prm[6], h = prm[7], bf = prm[10];
    bool flip = prm[11] > 0.5f;

    // exact bbox from 4 corners (projective coord funcs are edge-monotone) +-1 margin
    float minsx = 1e30f, maxsx = -1e30f, minsy = 1e30f, maxsy = -1e30f;
#pragma unroll
    for (int cy = 0; cy < 2; cy++) {
#pragma unroll
        for (int cxr = 0; cxr < 2; cxr++) {
            float Xg = (float)tx + (cxr ? 31.5f : 0.5f);
            float Yg = (float)ty + (cy ? 31.5f : 0.5f);
            float rden = 1.0f / (g * Xg + h * Yg + 1.0f);
            float sx = (a0 * Xg + a1 * Yg + a2) * rden - 0.5f;
            float sy = (a3 * Xg + a4 * Yg + a5) * rden - 0.5f;
            minsx = fminf(minsx, sx); maxsx = fmaxf(maxsx, sx);
            minsy = fminf(minsy, sy); maxsy = fmaxf(maxsy, sy);
        }
    }
    int x0b = min(max((int)floorf(minsx) - 1, 0), Wn - 1);
    int x1b = min(max((int)floorf(maxsx) + 2, 0), Wn - 1);
    int y0b = min(max((int)floorf(minsy) - 1, 0), Hn - 1);
    int y1b = min(max((int)floorf(maxsy) + 2, 0), Hn - 1);
    int bw = x1b - x0b + 1, bh = y1b - y0b + 1;
    bool use_lds = (bw <= TW) && (bh <= TH);     // block-uniform

    const size_t base = (size_t)p * PLANE;
    const float* xb = xin + base;
    const float* nb = noise + base;
    int tid = threadIdx.x;

    if (use_lds) {
        int lx = tid & 63, lr = tid >> 6;
        int xx = x0b + lx;
        bool xok = (lx < bw);
        int xsrc = flip ? (Wn - 1 - xx) : xx;
        for (int yy = y0b + lr; yy <= y1b; yy += 4) {
            if (xok)
                lds[(yy - y0b) * TSTRIDE + lx] =
                    (xb[yy * Wn + xsrc] + 0.625f * nb[yy * Wn + xx]) * bf;
        }
        __syncthreads();
    }

    int r = tid >> 3;
    int cg = tid & 7;
    int oy = ty + r, ox0 = tx + cg * 4;
    float Yg = (float)oy + 0.5f;
    float racc[4];
#pragma unroll
    for (int o = 0; o < 4; o++) {
        float Xg = (float)(ox0 + o) + 0.5f;
        float rden = 1.0f / (g * Xg + h * Yg + 1.0f);
        float sx = (a0 * Xg + a1 * Yg + a2) * rden - 0.5f;
        float sy = (a3 * Xg + a4 * Yg + a5) * rden - 0.5f;
        float fx0 = floorf(sx), fy0 = floorf(sy);
        float wx = sx - fx0, wy = sy - fy0;
        int x0 = (int)fx0, y0 = (int)fy0;
        float acc = 0.f;
#pragma unroll
        for (int dy = 0; dy < 2; dy++) {
            int yy = y0 + dy;
            float wyv = dy ? wy : 1.f - wy;
            bool yv = (unsigned)yy < (unsigned)Hn;
            int yc = min(max(yy, 0), Hn - 1);
#pragma unroll
            for (int dx = 0; dx < 2; dx++) {
                int xx = x0 + dx;
                float wxv = dx ? wx : 1.f - wx;
                bool v = yv && ((unsigned)xx < (unsigned)Wn);
                int xc = min(max(xx, 0), Wn - 1);
                float wgt = v ? wxv * wyv : 0.f;
                float val;
                if (use_lds) {
                    val = lds[(yc - y0b) * TSTRIDE + (xc - x0b)];
                } else {
                    int xsrc = flip ? (Wn - 1 - xc) : xc;
                    val = (xb[yc * Wn + xsrc] + 0.625f * nb[yc * Wn + xc]) * bf;
                }
                acc += val * wgt;
            }
        }
        racc[o] = acc;
    }
    *reinterpret_cast<float4*>(outP + base + (size_t)oy * Wn + ox0) =
        make_float4(racc[0], racc[1], racc[2], racc[3]);
}

// Stage 2: rotation bilinear, LDS-tiled (affine -> corner bbox exact).
__global__ __launch_bounds__(256) void rotate_kernel(const float* __restrict__ P,
                                                     const float* __restrict__ params,
                                                     float* __restrict__ outR) {
    __shared__ float lds[TH * TSTRIDE];
    int bi = blockIdx.x;
    int p = bi / 49;
    int t = bi % 49;
    int ty = (t / 7) * TILE;
    int tx = (t % 7) * TILE;
    int b = p / Cn;
    const float* prm = params + b * 12;
    float cs = prm[8], sn = prm[9];
    const float cx = (Wn - 1) * 0.5f;

    float minrx = 1e30f, maxrx = -1e30f, minry = 1e30f, maxry = -1e30f;
#pragma unroll
    for (int cy = 0; cy < 2; cy++) {
#pragma unroll
        for (int cxr = 0; cxr < 2; cxr++) {
            float dx = (float)(tx + (cxr ? 31 : 0)) - cx;
            float dy = (float)(ty + (cy ? 31 : 0)) - cx;
            float rx = cs * dx + sn * dy + cx;
            float ry = -sn * dx + cs * dy + cx;
            minrx = fminf(minrx, rx); maxrx = fmaxf(maxrx, rx);
            minry = fminf(minry, ry); maxry = fmaxf(maxry, ry);
        }
    }
    int x0b = min(max((int)floorf(minrx) - 1, 0), Wn - 1);
    int x1b = min(max((int)floorf(maxrx) + 2, 0), Wn - 1);
    int y0b = min(max((int)floorf(minry) - 1, 0), Hn - 1);
    int y1b = min(max((int)floorf(maxry) + 2, 0), Hn - 1);
    int bw = x1b - x0b + 1, bh = y1b - y0b + 1;
    bool use_lds = (bw <= TW) && (bh <= TH);

    const size_t base = (size_t)p * PLANE;
    const float* Pb = P + base;
    int tid = threadIdx.x;

    if (use_lds) {
        int lx = tid & 63, lr = tid >> 6;
        int xx = x0b + lx;
        bool xok = (lx < bw);
        for (int yy = y0b + lr; yy <= y1b; yy += 4) {
            if (xok)
                lds[(yy - y0b) * TSTRIDE + lx] = Pb[yy * Wn + xx];
        }
        __syncthreads();
    }

    int r = tid >> 3;
    int cg = tid & 7;
    int oy = ty + r, ox0 = tx + cg * 4;
    float dy = (float)oy - cx;
    float dx0 = (float)ox0 - cx;
    float rx0 = cs * dx0 + sn * dy + cx;
    float ry0 = -sn * dx0 + cs * dy + cx;
    float racc[4];
#pragma unroll
    for (int o = 0; o < 4; o++) {
        float rx = rx0 + cs * (float)o;
        float ry = ry0 - sn * (float)o;
        float fx0 = floorf(rx), fy0 = floorf(ry);
        float wx = rx - fx0, wy = ry - fy0;
        int x0 = (int)fx0, y0 = (int)fy0;
        float acc = 0.f;
#pragma unroll
        for (int ddy = 0; ddy < 2; ddy++) {
            int yy = y0 + ddy;
            float wyv = ddy ? wy : 1.f - wy;
            bool yv = (unsigned)yy < (unsigned)Hn;
            int yc = min(max(yy, 0), Hn - 1);
#pragma unroll
            for (int ddx = 0; ddx < 2; ddx++) {
                int xx = x0 + ddx;
                float wxv = ddx ? wx : 1.f - wx;
                bool v = yv && ((unsigned)xx < (unsigned)Wn);
                int xc = min(max(xx, 0), Wn - 1);
                float wgt = v ? wxv * wyv : 0.f;
                float val = use_lds ? lds[(yc - y0b) * TSTRIDE + (xc - x0b)]
                                    : Pb[yc * Wn + xc];
                acc += val * wgt;
            }
        }
        racc[o] = acc;
    }
    *reinterpret_cast<float4*>(outR + base + (size_t)oy * Wn + ox0) =
        make_float4(racc[0], racc[1], racc[2], racc[3]);
}

// Stage 3a: crop + horizontal bicubic 190->224.
__global__ void hpass_kernel(const float* __restrict__ R,
                             const int* __restrict__ crop_ij,
                             float* __restrict__ T) {
    unsigned int n = blockIdx.x * blockDim.x + threadIdx.x;
    unsigned int ox = n % Wn;
    unsigned int t = n / Wn;
    unsigned int y = t % CROPD;
    unsigned int p = t / CROPD;
    unsigned int b = p / Cn;
    int ci = crop_ij[b * 2 + 0];
    int cj = crop_ij[b * 2 + 1];
    float4 w = g_wt[ox];
    int i0 = g_i0[ox];
    const float* Rrow = R + (size_t)p * PLANE + (size_t)(y + ci) * Wn + cj;
    float wk[4] = {w.x, w.y, w.z, w.w};
    float acc = 0.f;
#pragma unroll
    for (int k = 0; k < 4; k++) {
        int ix = min(max(i0 - 1 + k, 0), CROPD - 1);
        acc += wk[k] * Rrow[ix];
    }
    T[(size_t)p * TPLANE + y * Wn + ox] = acc;
}

// Stage 3b: vertical bicubic 190->224, float4.
__global__ void vpass_kernel(const float* __restrict__ T,
                             float* __restrict__ out) {
    unsigned int n = blockIdx.x * blockDim.x + threadIdx.x;
    unsigned int qx = n % (Wn / 4);
    unsigned int t = n / (Wn / 4);
    unsigned int oy = t % Hn;
    unsigned int p = t / Hn;
    float4 w = g_wt[oy];
    int i0 = g_i0[oy];
    const float* Tp = T + (size_t)p * TPLANE;
    float wk[4] = {w.x, w.y, w.z, w.w};
    float4 acc = make_float4(0.f, 0.f, 0.f, 0.f);
#pragma unroll
    for (int k = 0; k < 4; k++) {
        int r = min(max(i0 - 1 + k, 0), CROPD - 1);
        float4 v = *reinterpret_cast<const float4*>(Tp + (size_t)r * Wn + qx * 4);
        acc.x += wk[k] * v.x;
        acc.y += wk[k] * v.y;
        acc.z += wk[k] * v.z;
        acc.w += wk[k] * v.w;
    }
    *reinterpret_cast<float4*>(out + (size_t)p * PLANE + oy * Wn + qx * 4) = acc;
}

extern "C" void kernel_launch(void* const* d_in, const int* in_sizes, int n_in,
                              void* d_out, int out_size, void* d_ws, size_t ws_size,
                              hipStream_t stream) {
    const float* x          = (const float*)d_in[0];
    const float* noise      = (const float*)d_in[1];
    const float* brightness = (const float*)d_in[2];
    const int*   flip_mask  = (const int*)d_in[3];
    const int*   ep_raw     = (const int*)d_in[4];
    const int*   angles     = (const int*)d_in[5];
    const int*   crop_ij    = (const int*)d_in[6];
    float* out = (float*)d_out;

    float* params = (float*)d_ws;                      // 256*12 floats
    float* Pbuf   = (float*)((char*)d_ws + 12288);     // persp out
    float* Tbuf   = Pbuf;                              // H-pass out reuses P
    float* Rbuf   = out;                               // rotate out staged in d_out

    int tileBlocks = 768 * 49;                         // 37,632
    int quadBlocks = (int)((NTOT / 4) / 256);
    int hBlocks    = (int)(((long long)Bn * Cn * CROPD * Wn) / 256);

    params_kernel<<<1, 256, 0, stream>>>(ep_raw, angles, brightness, flip_mask, params);
    persp_kernel<<<tileBlocks, 256, 0, stream>>>(x, noise, params, Pbuf);
    rotate_kernel<<<tileBlocks, 256, 0, stream>>>(Pbuf, params, Rbuf);
    hpass_kernel<<<hBlocks, 256, 0, stream>>>(Rbuf, crop_ij, Tbuf);
    vpass_kernel<<<quadBlocks, 256, 0, stream>>>(Tbuf, out);
}

// Round 4
// 379.275 us; speedup vs baseline: 2.4440x; 1.3802x over previous
//
#include <hip/hip_runtime.h>
#include <math.h>

#define Bn 256
#define Cn 3
#define Hn 224
#define Wn 224
#define CROPD 190

static constexpr long long NTOT = (long long)Bn * Cn * Hn * Wn;   // 38,535,168
static constexpr int PLANE = Hn * Wn;                              // 50176

// persp LDS source-tile geometry
#define TILE 32
#define TH 64
#define TW 64
#define TSTRIDE 65

// rotresize LDS geometry
#define PH 48
#define PSTR 49
#define RSTR 33

#define NWG (768 * 49)          // 37,632 blocks, both tile kernels
#define CHUNK (NWG / 8)         // 4704

// Bicubic weight tables (x and y identical: 190 -> 224, Keys a=-0.5,
// renormalized with out-of-range taps excluded).
__device__ int    g_i0[Wn];
__device__ float4 g_wt[Wn];

__device__ __forceinline__ float keys_cubic(float x) {
    if (x < 1.f) return ((1.5f * x - 2.5f) * x) * x + 1.f;
    if (x < 2.f) return ((-0.5f * x + 2.5f) * x - 4.f) * x + 2.f;
    return 0.f;
}

__device__ __forceinline__ int swz_block(int bid) {
    return (bid & 7) * CHUNK + (bid >> 3);   // XCD-aware, bijective (NWG%8==0)
}

// params[b*12 + {0..7: homography, 8: cos, 9: sin, 10: brightness, 11: flip}]
__global__ void params_kernel(const int* __restrict__ ep_raw,
                              const int* __restrict__ angles,
                              const float* __restrict__ brightness,
                              const int* __restrict__ flip_mask,
                              float* __restrict__ params) {
    int b = threadIdx.x;

    if (b < Wn) {
        float sf = ((float)b + 0.5f) * ((float)CROPD / (float)Wn) - 0.5f;
        int i0 = (int)floorf(sf);
        float w[4]; float s = 0.f;
#pragma unroll
        for (int k = 0; k < 4; k++) {
            int idx = i0 - 1 + k;
            float wk = (idx >= 0 && idx < CROPD) ? keys_cubic(fabsf(sf - (float)idx)) : 0.f;
            w[k] = wk; s += wk;
        }
        float inv = 1.f / s;
        g_i0[b] = i0;
        g_wt[b] = make_float4(w[0] * inv, w[1] * inv, w[2] * inv, w[3] * inv);
    }

    if (b >= Bn) return;

    const double offx[4] = {0.0, 195.0, 195.0, 0.0};
    const double offy[4] = {0.0, 0.0, 195.0, 195.0};
    const double sxc[4]  = {0.0, 223.0, 223.0, 0.0};
    const double syc[4]  = {0.0, 0.0, 223.0, 223.0};
    double M[8][9];
    for (int i = 0; i < 4; i++) {
        double ex = (double)ep_raw[b * 8 + i * 2 + 0] + offx[i];
        double ey = (double)ep_raw[b * 8 + i * 2 + 1] + offy[i];
        double sx = sxc[i], sy = syc[i];
        M[i][0] = ex; M[i][1] = ey; M[i][2] = 1.0;
        M[i][3] = 0.0; M[i][4] = 0.0; M[i][5] = 0.0;
        M[i][6] = -sx * ex; M[i][7] = -sx * ey; M[i][8] = sx;
        M[i + 4][0] = 0.0; M[i + 4][1] = 0.0; M[i + 4][2] = 0.0;
        M[i + 4][3] = ex; M[i + 4][4] = ey; M[i + 4][5] = 1.0;
        M[i + 4][6] = -sy * ex; M[i + 4][7] = -sy * ey; M[i + 4][8] = sy;
    }
    for (int k = 0; k < 8; k++) {
        int piv = k; double best = fabs(M[k][k]);
        for (int r = k + 1; r < 8; r++) {
            double v = fabs(M[r][k]);
            if (v > best) { best = v; piv = r; }
        }
        if (piv != k)
            for (int j = 0; j < 9; j++) { double t = M[k][j]; M[k][j] = M[piv][j]; M[piv][j] = t; }
        double inv = 1.0 / M[k][k];
        for (int r = k + 1; r < 8; r++) {
            double f = M[r][k] * inv;
            M[r][k] = 0.0;
            for (int j = k + 1; j < 9; j++) M[r][j] -= f * M[k][j];
        }
    }
    double sol[8];
    for (int k = 7; k >= 0; k--) {
        double s = M[k][8];
        for (int j = k + 1; j < 8; j++) s -= M[k][j] * sol[j];
        sol[k] = s / M[k][k];
    }
    float* p = params + b * 12;
    for (int j = 0; j < 8; j++) p[j] = (float)sol[j];
    double th = ((double)angles[b] - 16.0) * (M_PI / 180.0);
    p[8]  = (float)cos(th);
    p[9]  = (float)sin(th);
    p[10] = 0.85f + 0.3f * brightness[b];
    p[11] = (flip_mask[b] > 0) ? 1.0f : 0.0f;
}

// Stage 1: flip + noise + brightness + perspective bilinear, LDS-tiled.
__global__ __launch_bounds__(256) void persp_kernel(const float* __restrict__ xin,
                                                    const float* __restrict__ noise,
                                                    const float* __restrict__ params,
                                                    float* __restrict__ outP) {
    __shared__ float lds[TH * TSTRIDE];
    int bi = swz_block(blockIdx.x);
    int p = bi / 49;
    int t = bi % 49;
    int ty = (t / 7) * TILE;
    int tx = (t % 7) * TILE;
    int b = p / Cn;
    const float* prm = params + b * 12;
    float a0 = prm[0], a1 = prm[1], a2 = prm[2];
    float a3 = prm[3], a4 = prm[4], a5 = prm[5];
    float g = prm[6], h = prm[7], bf = prm[10];
    bool flip = prm[11] > 0.5f;

    float minsx = 1e30f, maxsx = -1e30f, minsy = 1e30f, maxsy = -1e30f;
#pragma unroll
    for (int cy = 0; cy < 2; cy++) {
#pragma unroll
        for (int cxr = 0; cxr < 2; cxr++) {
            float Xg = (float)tx + (cxr ? 31.5f : 0.5f);
            float Yg = (float)ty + (cy ? 31.5f : 0.5f);
            float rden = 1.0f / (g * Xg + h * Yg + 1.0f);
            float sx = (a0 * Xg + a1 * Yg + a2) * rden - 0.5f;
            float sy = (a3 * Xg + a4 * Yg + a5) * rden - 0.5f;
            minsx = fminf(minsx, sx); maxsx = fmaxf(maxsx, sx);
            minsy = fminf(minsy, sy); maxsy = fmaxf(maxsy, sy);
        }
    }
    int x0b = min(max((int)floorf(minsx) - 1, 0), Wn - 1);
    int x1b = min(max((int)floorf(maxsx) + 2, 0), Wn - 1);
    int y0b = min(max((int)floorf(minsy) - 1, 0), Hn - 1);
    int y1b = min(max((int)floorf(maxsy) + 2, 0), Hn - 1);
    int bw = x1b - x0b + 1, bh = y1b - y0b + 1;
    bool use_lds = (bw <= TW) && (bh <= TH);
    bool interior = (minsx >= 0.5f) && (maxsx <= 222.0f) &&
                    (minsy >= 0.5f) && (maxsy <= 222.0f);

    const size_t base = (size_t)p * PLANE;
    const float* xb = xin + base;
    const float* nb = noise + base;
    int tid = threadIdx.x;

    if (use_lds) {
        int lx = tid & 63, lr = tid >> 6;
        int xx = x0b + lx;
        bool xok = (lx < bw);
        int xsrc = flip ? (Wn - 1 - xx) : xx;
        for (int yy = y0b + lr; yy <= y1b; yy += 4) {
            if (xok)
                lds[(yy - y0b) * TSTRIDE + lx] =
                    (xb[yy * Wn + xsrc] + 0.625f * nb[yy * Wn + xx]) * bf;
        }
        __syncthreads();
    }

    int r = tid >> 3;
    int cg = tid & 7;
    int oy = ty + r, ox0 = tx + cg * 4;
    float Yg = (float)oy + 0.5f;
    float racc[4];
    if (use_lds && interior) {
#pragma unroll
        for (int o = 0; o < 4; o++) {
            float Xg = (float)(ox0 + o) + 0.5f;
            float rden = 1.0f / (g * Xg + h * Yg + 1.0f);
            float sx = (a0 * Xg + a1 * Yg + a2) * rden - 0.5f;
            float sy = (a3 * Xg + a4 * Yg + a5) * rden - 0.5f;
            float fx0 = floorf(sx), fy0 = floorf(sy);
            float wx = sx - fx0, wy = sy - fy0;
            const float* q = &lds[((int)fy0 - y0b) * TSTRIDE + ((int)fx0 - x0b)];
            float top = q[0] + wx * (q[1] - q[0]);
            float bot = q[TSTRIDE] + wx * (q[TSTRIDE + 1] - q[TSTRIDE]);
            racc[o] = top + wy * (bot - top);
        }
    } else {
#pragma unroll
        for (int o = 0; o < 4; o++) {
            float Xg = (float)(ox0 + o) + 0.5f;
            float rden = 1.0f / (g * Xg + h * Yg + 1.0f);
            float sx = (a0 * Xg + a1 * Yg + a2) * rden - 0.5f;
            float sy = (a3 * Xg + a4 * Yg + a5) * rden - 0.5f;
            float fx0 = floorf(sx), fy0 = floorf(sy);
            float wx = sx - fx0, wy = sy - fy0;
            int x0 = (int)fx0, y0 = (int)fy0;
            float acc = 0.f;
#pragma unroll
            for (int dy = 0; dy < 2; dy++) {
                int yy = y0 + dy;
                float wyv = dy ? wy : 1.f - wy;
                bool yv = (unsigned)yy < (unsigned)Hn;
                int yc = min(max(yy, 0), Hn - 1);
#pragma unroll
                for (int dx = 0; dx < 2; dx++) {
                    int xx = x0 + dx;
                    float wxv = dx ? wx : 1.f - wx;
                    bool v = yv && ((unsigned)xx < (unsigned)Wn);
                    int xc = min(max(xx, 0), Wn - 1);
                    float wgt = v ? wxv * wyv : 0.f;
                    float val;
                    if (use_lds) {
                        val = lds[(yc - y0b) * TSTRIDE + (xc - x0b)];
                    } else {
                        int xsrc = flip ? (Wn - 1 - xc) : xc;
                        val = (xb[yc * Wn + xsrc] + 0.625f * nb[yc * Wn + xc]) * bf;
                    }
                    acc += val * wgt;
                }
            }
            racc[o] = acc;
        }
    }
    *reinterpret_cast<float4*>(outP + base + (size_t)oy * Wn + ox0) =
        make_float4(racc[0], racc[1], racc[2], racc[3]);
}

// Stage 2 (fused): rotation + crop + bicubic H-pass + V-pass -> out tile 32x32.
// Arithmetic identical to the previous rotate/hpass/vpass chain.
__global__ __launch_bounds__(256) void rotresize_kernel(const float* __restrict__ P,
                                                        const float* __restrict__ params,
                                                        const int* __restrict__ crop_ij,
                                                        float* __restrict__ out) {
    __shared__ float Plds[PH * PSTR];      // staged P bbox
    __shared__ float Rlds[32 * RSTR];      // rotated tile (cropped coords rows/cols)
    __shared__ float Tlds[32 * RSTR];      // H-pass tile
    int bi = swz_block(blockIdx.x);
    int p = bi / 49;
    int t = bi % 49;
    int ty = (t / 7) * TILE;
    int tx = (t % 7) * TILE;
    int b = p / Cn;
    const float* prm = params + b * 12;
    float cs = prm[8], sn = prm[9];
    int ci = crop_ij[b * 2 + 0];
    int cj = crop_ij[b * 2 + 1];

    // T rows / R cols needed by this tile (cropped coords, clamp-inclusive)
    int iymin = max(g_i0[ty] - 1, 0);
    int iymax = min(g_i0[ty + 31] + 2, CROPD - 1);
    int nTy = iymax - iymin + 1;                 // <= 31
    int jmin = max(g_i0[tx] - 1, 0);
    int jmax = min(g_i0[tx + 31] + 2, CROPD - 1);
    int nRx = jmax - jmin + 1;                   // <= 31
    int ry0 = iymin + ci, ry1 = iymax + ci;      // global rows of R rect
    int rx0 = jmin + cj, rx1 = jmax + cj;        // global cols

    // rotation source bbox over the R rect (affine -> corner-exact)
    const float cxc = (Wn - 1) * 0.5f;
    float minrx = 1e30f, maxrx = -1e30f, minry = 1e30f, maxry = -1e30f;
#pragma unroll
    for (int cy = 0; cy < 2; cy++) {
#pragma unroll
        for (int cxr = 0; cxr < 2; cxr++) {
            float dx = (float)(cxr ? rx1 : rx0) - cxc;
            float dy = (float)(cy ? ry1 : ry0) - cxc;
            float rx = cs * dx + sn * dy + cxc;
            float ry = -sn * dx + cs * dy + cxc;
            minrx = fminf(minrx, rx); maxrx = fmaxf(maxrx, rx);
            minry = fminf(minry, ry); maxry = fmaxf(maxry, ry);
        }
    }
    int x0b = min(max((int)floorf(minrx) - 1, 0), Wn - 1);
    int x1b = min(max((int)floorf(maxrx) + 2, 0), Wn - 1);
    int y0b = min(max((int)floorf(minry) - 1, 0), Hn - 1);
    int y1b = min(max((int)floorf(maxry) + 2, 0), Hn - 1);
    int bw = x1b - x0b + 1, bh = y1b - y0b + 1;
    bool use_lds = (bw <= PH) && (bh <= PH);     // <=43 always in practice
    bool interior = (minrx >= 0.5f) && (maxrx <= 222.0f) &&
                    (minry >= 0.5f) && (maxry <= 222.0f);

    const float* Pb = P + (size_t)p * PLANE;
    int tid = threadIdx.x;

    if (use_lds) {
        int lx = tid & 63, lr = tid >> 6;
        bool xok = (lx < bw);
        for (int yy = y0b + lr; yy <= y1b; yy += 4) {
            if (xok) Plds[(yy - y0b) * PSTR + lx] = Pb[yy * Wn + x0b + lx];
        }
        __syncthreads();
    }

    // ---- R tile: rotation bilinear over the R rect ----
    if (use_lds && interior) {
#pragma unroll
        for (int it = 0; it < 4; it++) {
            int idx = it * 256 + tid;
            int rr = idx >> 5, rc = idx & 31;
            if (rr < nTy && rc < nRx) {
                float dx = (float)(rx0 + rc) - cxc;
                float dy = (float)(ry0 + rr) - cxc;
                float srx = cs * dx + sn * dy + cxc;
                float sry = -sn * dx + cs * dy + cxc;
                float fx0 = floorf(srx), fy0 = floorf(sry);
                float wx = srx - fx0, wy = sry - fy0;
                const float* q = &Plds[((int)fy0 - y0b) * PSTR + ((int)fx0 - x0b)];
                float top = q[0] + wx * (q[1] - q[0]);
                float bot = q[PSTR] + wx * (q[PSTR + 1] - q[PSTR]);
                Rlds[rr * RSTR + rc] = top + wy * (bot - top);
            }
        }
    } else {
#pragma unroll
        for (int it = 0; it < 4; it++) {
            int idx = it * 256 + tid;
            int rr = idx >> 5, rc = idx & 31;
            if (rr < nTy && rc < nRx) {
                float dx = (float)(rx0 + rc) - cxc;
                float dy = (float)(ry0 + rr) - cxc;
                float srx = cs * dx + sn * dy + cxc;
                float sry = -sn * dx + cs * dy + cxc;
                float fx0 = floorf(srx), fy0 = floorf(sry);
                float wx = srx - fx0, wy = sry - fy0;
                int x0 = (int)fx0, y0 = (int)fy0;
                float acc = 0.f;
#pragma unroll
                for (int ddy = 0; ddy < 2; ddy++) {
                    int yy = y0 + ddy;
                    float wyv = ddy ? wy : 1.f - wy;
                    bool yv = (unsigned)yy < (unsigned)Hn;
                    int yc = min(max(yy, 0), Hn - 1);
#pragma unroll
                    for (int ddx = 0; ddx < 2; ddx++) {
                        int xx = x0 + ddx;
                        float wxv = ddx ? wx : 1.f - wx;
                        bool v = yv && ((unsigned)xx < (unsigned)Wn);
                        int xc = min(max(xx, 0), Wn - 1);
                        float wgt = v ? wxv * wyv : 0.f;
                        float val = use_lds ? Plds[(yc - y0b) * PSTR + (xc - x0b)]
                                            : Pb[yc * Wn + xc];
                        acc += val * wgt;
                    }
                }
                Rlds[rr * RSTR + rc] = acc;
            }
        }
    }
    __syncthreads();

    // ---- T tile: horizontal bicubic (cols tx..tx+31) ----
#pragma unroll
    for (int it = 0; it < 4; it++) {
        int idx = it * 256 + tid;
        int rr = idx >> 5, oc = idx & 31;
        if (rr < nTy) {
            int ox = tx + oc;
            float4 w = g_wt[ox];
            int j0 = g_i0[ox];
            float wk[4] = {w.x, w.y, w.z, w.w};
            float acc = 0.f;
#pragma unroll
            for (int k = 0; k < 4; k++) {
                int jc = min(max(j0 - 1 + k, 0), CROPD - 1) - jmin;
                acc += wk[k] * Rlds[rr * RSTR + jc];
            }
            Tlds[rr * RSTR + oc] = acc;
        }
    }
    __syncthreads();

    // ---- V-pass: 4 outputs/thread, float4 coalesced store ----
    int r = tid >> 3, cg = tid & 7;
    int oy = ty + r, ox0 = tx + cg * 4;
    float4 w = g_wt[oy];
    int i0y = g_i0[oy];
    float wk[4] = {w.x, w.y, w.z, w.w};
    float4 acc = make_float4(0.f, 0.f, 0.f, 0.f);
#pragma unroll
    for (int k = 0; k < 4; k++) {
        int iyc = min(max(i0y - 1 + k, 0), CROPD - 1) - iymin;
        const float* row = &Tlds[iyc * RSTR + cg * 4];
        acc.x += wk[k] * row[0];
        acc.y += wk[k] * row[1];
        acc.z += wk[k] * row[2];
        acc.w += wk[k] * row[3];
    }
    *reinterpret_cast<float4*>(out + (size_t)p * PLANE + (size_t)oy * Wn + ox0) = acc;
}

extern "C" void kernel_launch(void* const* d_in, const int* in_sizes, int n_in,
                              void* d_out, int out_size, void* d_ws, size_t ws_size,
                              hipStream_t stream) {
    const float* x          = (const float*)d_in[0];
    const float* noise      = (const float*)d_in[1];
    const float* brightness = (const float*)d_in[2];
    const int*   flip_mask  = (const int*)d_in[3];
    const int*   ep_raw     = (const int*)d_in[4];
    const int*   angles     = (const int*)d_in[5];
    const int*   crop_ij    = (const int*)d_in[6];
    float* out = (float*)d_out;

    float* params = (float*)d_ws;                      // 256*12 floats
    float* Pbuf   = (float*)((char*)d_ws + 12288);     // persp out (B*C*H*W f32)

    params_kernel<<<1, 256, 0, stream>>>(ep_raw, angles, brightness, flip_mask, params);
    persp_kernel<<<NWG, 256, 0, stream>>>(x, noise, params, Pbuf);
    rotresize_kernel<<<NWG, 256, 0, stream>>>(Pbuf, params, crop_ij, out);
}

// Round 5
// 273.563 us; speedup vs baseline: 3.3884x; 1.3864x over previous
//
#include <hip/hip_runtime.h>
#include <math.h>

#define Bn 256
#define Cn 3
#define Hn 224
#define Wn 224
#define CROPD 190

static constexpr long long NTOT = (long long)Bn * Cn * Hn * Wn;   // 38,535,168
static constexpr int PLANE = Hn * Wn;                              // 50176

#define TILE 32
#define TSTR 68            // persp LDS row stride (floats, mult of 4)
#define PH 48              // rotresize staged P rows/cols max
#define PSTR 52            // P LDS stride
#define RSTR 40            // R/T tile stride (mult of 4; banks 8*row)

#define NWG (768 * 49)     // 37,632
#define CHUNK (NWG / 8)

__device__ int    g_i0[Wn];
__device__ float4 g_wt[Wn];

__device__ __forceinline__ float keys_cubic(float x) {
    if (x < 1.f) return ((1.5f * x - 2.5f) * x) * x + 1.f;
    if (x < 2.f) return ((-0.5f * x + 2.5f) * x - 4.f) * x + 2.f;
    return 0.f;
}
__device__ __forceinline__ float rflf(float v) {
    return __int_as_float(__builtin_amdgcn_readfirstlane(__float_as_int(v)));
}
__device__ __forceinline__ int rfli(int v) { return __builtin_amdgcn_readfirstlane(v); }
__device__ __forceinline__ int swz_block(int bid) {
    return (bid & 7) * CHUNK + (bid >> 3);   // bijective, NWG%8==0
}

// params[b*12 + {0..7: homography, 8: cos, 9: sin, 10: brightness, 11: flip}]
__global__ void params_kernel(const int* __restrict__ ep_raw,
                              const int* __restrict__ angles,
                              const float* __restrict__ brightness,
                              const int* __restrict__ flip_mask,
                              float* __restrict__ params) {
    int b = threadIdx.x;

    if (b < Wn) {
        float sf = ((float)b + 0.5f) * ((float)CROPD / (float)Wn) - 0.5f;
        int i0 = (int)floorf(sf);
        float w[4]; float s = 0.f;
#pragma unroll
        for (int k = 0; k < 4; k++) {
            int idx = i0 - 1 + k;
            float wk = (idx >= 0 && idx < CROPD) ? keys_cubic(fabsf(sf - (float)idx)) : 0.f;
            w[k] = wk; s += wk;
        }
        float inv = 1.f / s;
        g_i0[b] = i0;
        g_wt[b] = make_float4(w[0] * inv, w[1] * inv, w[2] * inv, w[3] * inv);
    }

    if (b >= Bn) return;

    const double offx[4] = {0.0, 195.0, 195.0, 0.0};
    const double offy[4] = {0.0, 0.0, 195.0, 195.0};
    const double sxc[4]  = {0.0, 223.0, 223.0, 0.0};
    const double syc[4]  = {0.0, 0.0, 223.0, 223.0};
    double M[8][9];
    for (int i = 0; i < 4; i++) {
        double ex = (double)ep_raw[b * 8 + i * 2 + 0] + offx[i];
        double ey = (double)ep_raw[b * 8 + i * 2 + 1] + offy[i];
        double sx = sxc[i], sy = syc[i];
        M[i][0] = ex; M[i][1] = ey; M[i][2] = 1.0;
        M[i][3] = 0.0; M[i][4] = 0.0; M[i][5] = 0.0;
        M[i][6] = -sx * ex; M[i][7] = -sx * ey; M[i][8] = sx;
        M[i + 4][0] = 0.0; M[i + 4][1] = 0.0; M[i + 4][2] = 0.0;
        M[i + 4][3] = ex; M[i + 4][4] = ey; M[i + 4][5] = 1.0;
        M[i + 4][6] = -sy * ex; M[i + 4][7] = -sy * ey; M[i + 4][8] = sy;
    }
    for (int k = 0; k < 8; k++) {
        int piv = k; double best = fabs(M[k][k]);
        for (int r = k + 1; r < 8; r++) {
            double v = fabs(M[r][k]);
            if (v > best) { best = v; piv = r; }
        }
        if (piv != k)
            for (int j = 0; j < 9; j++) { double tt = M[k][j]; M[k][j] = M[piv][j]; M[piv][j] = tt; }
        double inv = 1.0 / M[k][k];
        for (int r = k + 1; r < 8; r++) {
            double f = M[r][k] * inv;
            M[r][k] = 0.0;
            for (int j = k + 1; j < 9; j++) M[r][j] -= f * M[k][j];
        }
    }
    double sol[8];
    for (int k = 7; k >= 0; k--) {
        double s = M[k][8];
        for (int j = k + 1; j < 8; j++) s -= M[k][j] * sol[j];
        sol[k] = s / M[k][k];
    }
    float* p = params + b * 12;
    for (int j = 0; j < 8; j++) p[j] = (float)sol[j];
    double th = ((double)angles[b] - 16.0) * (M_PI / 180.0);
    p[8]  = (float)cos(th);
    p[9]  = (float)sin(th);
    p[10] = 0.85f + 0.3f * brightness[b];
    p[11] = (flip_mask[b] > 0) ? 1.0f : 0.0f;
}

// Per-(batch,tile) bboxes + interior flags. 49 blocks x 256 = 12544 threads.
__global__ void meta_kernel(const float* __restrict__ params,
                            const int* __restrict__ crop_ij,
                            int4* __restrict__ pmeta,
                            int4* __restrict__ rmeta) {
    int bt = blockIdx.x * 256 + threadIdx.x;    // < 12544
    int b = bt / 49, t = bt % 49;
    int ty = (t / 7) * TILE, tx = (t % 7) * TILE;
    const float* prm = params + b * 12;

    // ---- persp bbox (identical formulas to R4) ----
    {
        float a0 = prm[0], a1 = prm[1], a2 = prm[2];
        float a3 = prm[3], a4 = prm[4], a5 = prm[5];
        float g = prm[6], h = prm[7];
        float minsx = 1e30f, maxsx = -1e30f, minsy = 1e30f, maxsy = -1e30f;
#pragma unroll
        for (int cy = 0; cy < 2; cy++) {
#pragma unroll
            for (int cxr = 0; cxr < 2; cxr++) {
                float Xg = (float)tx + (cxr ? 31.5f : 0.5f);
                float Yg = (float)ty + (cy ? 31.5f : 0.5f);
                float rden = 1.0f / (g * Xg + h * Yg + 1.0f);
                float sx = (a0 * Xg + a1 * Yg + a2) * rden - 0.5f;
                float sy = (a3 * Xg + a4 * Yg + a5) * rden - 0.5f;
                minsx = fminf(minsx, sx); maxsx = fmaxf(maxsx, sx);
                minsy = fminf(minsy, sy); maxsy = fmaxf(maxsy, sy);
            }
        }
        int x0b = min(max((int)floorf(minsx) - 1, 0), Wn - 1);
        int x1b = min(max((int)floorf(maxsx) + 2, 0), Wn - 1);
        int y0b = min(max((int)floorf(minsy) - 1, 0), Hn - 1);
        int y1b = min(max((int)floorf(maxsy) + 2, 0), Hn - 1);
        x0b &= ~3;
        int bw = x1b - x0b + 1, bh = y1b - y0b + 1;
        int inter = (minsx >= 0.5f && maxsx <= 222.0f &&
                     minsy >= 0.5f && maxsy <= 222.0f) ? 1 : 0;
        pmeta[bt] = make_int4(x0b, y0b, bw | (inter << 16), bh);
    }

    // ---- rot bbox over R rect ----
    {
        float cs = prm[8], sn = prm[9];
        int ci = crop_ij[b * 2 + 0], cj = crop_ij[b * 2 + 1];
        int iymin = max(g_i0[ty] - 1, 0);
        int iymax = min(g_i0[ty + 31] + 2, CROPD - 1);
        int jmin = max(g_i0[tx] - 1, 0);
        int jmax = min(g_i0[tx + 31] + 2, CROPD - 1);
        int ry0 = iymin + ci, ry1 = iymax + ci;
        int rx0 = jmin + cj, rx1 = jmax + cj;
        const float cxc = (Wn - 1) * 0.5f;
        float minrx = 1e30f, maxrx = -1e30f, minry = 1e30f, maxry = -1e30f;
#pragma unroll
        for (int cy = 0; cy < 2; cy++) {
#pragma unroll
            for (int cxr = 0; cxr < 2; cxr++) {
                float dx = (float)(cxr ? rx1 : rx0) - cxc;
                float dy = (float)(cy ? ry1 : ry0) - cxc;
                float rx = cs * dx + sn * dy + cxc;
                float ry = -sn * dx + cs * dy + cxc;
                minrx = fminf(minrx, rx); maxrx = fmaxf(maxrx, rx);
                minry = fminf(minry, ry); maxry = fmaxf(maxry, ry);
            }
        }
        int x0b = min(max((int)floorf(minrx) - 1, 0), Wn - 1);
        int x1b = min(max((int)floorf(maxrx) + 2, 0), Wn - 1);
        int y0b = min(max((int)floorf(minry) - 1, 0), Hn - 1);
        int y1b = min(max((int)floorf(maxry) + 2, 0), Hn - 1);
        x0b &= ~3;
        int bw = x1b - x0b + 1, bh = y1b - y0b + 1;
        int inter = (minrx >= 0.5f && maxrx <= 222.0f &&
                     minry >= 0.5f && maxry <= 222.0f) ? 1 : 0;
        rmeta[bt] = make_int4(x0b, y0b, bw | (inter << 16), bh);
    }
}

// Stage 1: flip + noise + brightness + perspective bilinear, LDS-tiled.
__global__ __launch_bounds__(256) void persp_kernel(const float* __restrict__ xin,
                                                    const float* __restrict__ noise,
                                                    const float* __restrict__ params,
                                                    const int4* __restrict__ pmeta,
                                                    float* __restrict__ outP) {
    __shared__ __align__(16) float lds[64 * TSTR];
    int bi = swz_block(blockIdx.x);
    int p = bi / 49;
    int t = bi % 49;
    int ty = (t / 7) * TILE;
    int tx = (t % 7) * TILE;
    int b = p / Cn;
    int4 m = pmeta[b * 49 + t];
    int x0b = m.x, y0b = m.y;
    int bw = m.z & 0xffff;
    bool interior = (m.z >> 16) != 0;
    int bh = m.w;
    int y1b = y0b + bh - 1;
    bool use_lds = (bw <= 64) && (bh <= 64);

    const float* prm = params + b * 12;
    float a0 = rflf(prm[0]), a1 = rflf(prm[1]), a2 = rflf(prm[2]);
    float a3 = rflf(prm[3]), a4 = rflf(prm[4]), a5 = rflf(prm[5]);
    float g = rflf(prm[6]), h = rflf(prm[7]), bf = rflf(prm[10]);
    bool flip = rflf(prm[11]) > 0.5f;

    const size_t base = (size_t)p * PLANE;
    const float* xb = xin + base;
    const float* nb = noise + base;
    int tid = threadIdx.x;

    if (use_lds) {
        int bwq = (bw + 3) >> 2;                    // <= 16
        int sh = (bwq <= 8) ? 3 : 4;
        int c4 = tid & ((1 << sh) - 1);
        int r0 = tid >> sh;
        int rstep = 256 >> sh;                      // 32 or 16
        bool cok = c4 < bwq;
        for (int yy = y0b + r0; yy <= y1b; yy += rstep) {
            if (cok) {
                int xl = min(x0b + c4 * 4, Wn - 4);     // stays 4-aligned (220%4==0)
                float4 nv = *reinterpret_cast<const float4*>(&nb[yy * Wn + xl]);
                float4 xv;
                if (flip) {
                    float4 xr = *reinterpret_cast<const float4*>(&xb[yy * Wn + (Wn - 4 - xl)]);
                    xv = make_float4(xr.w, xr.z, xr.y, xr.x);
                } else {
                    xv = *reinterpret_cast<const float4*>(&xb[yy * Wn + xl]);
                }
                float4 f = make_float4((xv.x + 0.625f * nv.x) * bf,
                                       (xv.y + 0.625f * nv.y) * bf,
                                       (xv.z + 0.625f * nv.z) * bf,
                                       (xv.w + 0.625f * nv.w) * bf);
                *reinterpret_cast<float4*>(&lds[(yy - y0b) * TSTR + (xl - x0b)]) = f;
            }
        }
        __syncthreads();
    }

    int r = tid >> 3;
    int cg = tid & 7;
    int oy = ty + r, ox0 = tx + cg * 4;
    float Yg = (float)oy + 0.5f;
    float Xg0 = (float)ox0 + 0.5f;
    float nx = a0 * Xg0 + a1 * Yg + a2;
    float ny = a3 * Xg0 + a4 * Yg + a5;
    float dn = g * Xg0 + h * Yg + 1.0f;
    float racc[4];
    if (use_lds && interior) {
#pragma unroll
        for (int o = 0; o < 4; o++) {
            float rden = __builtin_amdgcn_rcpf(dn);
            float sx = nx * rden - 0.5f;
            float sy = ny * rden - 0.5f;
            float fx0 = floorf(sx), fy0 = floorf(sy);
            float wx = sx - fx0, wy = sy - fy0;
            const float* q = &lds[((int)fy0 - y0b) * TSTR + ((int)fx0 - x0b)];
            float top = q[0] + wx * (q[1] - q[0]);
            float bot = q[TSTR] + wx * (q[TSTR + 1] - q[TSTR]);
            racc[o] = top + wy * (bot - top);
            nx += a0; ny += a3; dn += g;
        }
    } else {
#pragma unroll
        for (int o = 0; o < 4; o++) {
            float rden = __builtin_amdgcn_rcpf(dn);
            float sx = nx * rden - 0.5f;
            float sy = ny * rden - 0.5f;
            float fx0 = floorf(sx), fy0 = floorf(sy);
            float wx = sx - fx0, wy = sy - fy0;
            int x0 = (int)fx0, y0 = (int)fy0;
            float acc = 0.f;
#pragma unroll
            for (int dy = 0; dy < 2; dy++) {
                int yy = y0 + dy;
                float wyv = dy ? wy : 1.f - wy;
                bool yv = (unsigned)yy < (unsigned)Hn;
                int yc = min(max(yy, 0), Hn - 1);
#pragma unroll
                for (int dx = 0; dx < 2; dx++) {
                    int xx = x0 + dx;
                    float wxv = dx ? wx : 1.f - wx;
                    bool v = yv && ((unsigned)xx < (unsigned)Wn);
                    int xc = min(max(xx, 0), Wn - 1);
                    float wgt = v ? wxv * wyv : 0.f;
                    float val;
                    if (use_lds) {
                        val = lds[(yc - y0b) * TSTR + (xc - x0b)];
                    } else {
                        int xsrc = flip ? (Wn - 1 - xc) : xc;
                        val = (xb[yc * Wn + xsrc] + 0.625f * nb[yc * Wn + xc]) * bf;
                    }
                    acc += val * wgt;
                }
            }
            racc[o] = acc;
            nx += a0; ny += a3; dn += g;
        }
    }
    *reinterpret_cast<float4*>(outP + base + (size_t)oy * Wn + ox0) =
        make_float4(racc[0], racc[1], racc[2], racc[3]);
}

// Stage 2 (fused): rotation + crop + bicubic H + V -> 32x32 out tile.
__global__ __launch_bounds__(256) void rotresize_kernel(const float* __restrict__ P,
                                                        const float* __restrict__ params,
                                                        const int* __restrict__ crop_ij,
                                                        const int4* __restrict__ rmeta,
                                                        float* __restrict__ out) {
    __shared__ __align__(16) float Plds[PH * PSTR];
    __shared__ __align__(16) float Rlds[32 * RSTR];
    __shared__ __align__(16) float Tlds[32 * RSTR];
    int bi = swz_block(blockIdx.x);
    int p = bi / 49;
    int t = bi % 49;
    int ty = (t / 7) * TILE;
    int tx = (t % 7) * TILE;
    int b = p / Cn;
    int4 m = rmeta[b * 49 + t];
    int x0b = m.x, y0b = m.y;
    int bw = m.z & 0xffff;
    bool interior = (m.z >> 16) != 0;
    int bh = m.w;
    int y1b = y0b + bh - 1;
    bool use_lds = (bw <= PH) && (bh <= PH);

    const float* prm = params + b * 12;
    float cs = rflf(prm[8]), sn = rflf(prm[9]);
    int ci = rfli(crop_ij[b * 2 + 0]);
    int cj = rfli(crop_ij[b * 2 + 1]);
    int iymin = max(g_i0[ty] - 1, 0);
    int nTy = min(g_i0[ty + 31] + 2, CROPD - 1) - iymin + 1;
    int jmin = max(g_i0[tx] - 1, 0);
    int nRx = min(g_i0[tx + 31] + 2, CROPD - 1) - jmin + 1;
    int rx0 = jmin + cj, ry0 = iymin + ci;
    const float cxc = (Wn - 1) * 0.5f;

    const float* Pb = P + (size_t)p * PLANE;
    int tid = threadIdx.x;

    if (use_lds) {
        int bwq = (bw + 3) >> 2;                    // <= 12
        int sh = (bwq <= 8) ? 3 : 4;
        int c4 = tid & ((1 << sh) - 1);
        int r0 = tid >> sh;
        int rstep = 256 >> sh;
        bool cok = c4 < bwq;
        for (int yy = y0b + r0; yy <= y1b; yy += rstep) {
            if (cok) {
                int xl = min(x0b + c4 * 4, Wn - 4);
                float4 v = *reinterpret_cast<const float4*>(&Pb[yy * Wn + xl]);
                *reinterpret_cast<float4*>(&Plds[(yy - y0b) * PSTR + (xl - x0b)]) = v;
            }
        }
        __syncthreads();
    }

    // ---- R phase: rotation bilinear over the R rect ----
    {
        int rc = tid & 31;
        int rbase = tid >> 5;                      // 0..7
        bool cok = rc < nRx;
        float dxc = (float)(rx0 + rc) - cxc;
        float bx = cs * dxc + cxc;                 // srx = bx + sn*dyr
        float by = -sn * dxc + cxc;                // sry = by + cs*dyr
        if (use_lds && interior) {
#pragma unroll
            for (int it = 0; it < 4; it++) {
                int rr = it * 8 + rbase;
                if (rr < nTy && cok) {
                    float dyr = (float)(ry0 + rr) - cxc;
                    float srx = bx + sn * dyr;
                    float sry = by + cs * dyr;
                    float fx0 = floorf(srx), fy0 = floorf(sry);
                    float wx = srx - fx0, wy = sry - fy0;
                    const float* q = &Plds[((int)fy0 - y0b) * PSTR + ((int)fx0 - x0b)];
                    float top = q[0] + wx * (q[1] - q[0]);
                    float bot = q[PSTR] + wx * (q[PSTR + 1] - q[PSTR]);
                    Rlds[rr * RSTR + rc] = top + wy * (bot - top);
                }
            }
        } else {
#pragma unroll
            for (int it = 0; it < 4; it++) {
                int rr = it * 8 + rbase;
                if (rr < nTy && cok) {
                    float dyr = (float)(ry0 + rr) - cxc;
                    float srx = bx + sn * dyr;
                    float sry = by + cs * dyr;
                    float fx0 = floorf(srx), fy0 = floorf(sry);
                    float wx = srx - fx0, wy = sry - fy0;
                    int x0 = (int)fx0, y0 = (int)fy0;
                    float acc = 0.f;
#pragma unroll
                    for (int ddy = 0; ddy < 2; ddy++) {
                        int yy = y0 + ddy;
                        float wyv = ddy ? wy : 1.f - wy;
                        bool yv = (unsigned)yy < (unsigned)Hn;
                        int yc = min(max(yy, 0), Hn - 1);
#pragma unroll
                        for (int ddx = 0; ddx < 2; ddx++) {
                            int xx = x0 + ddx;
                            float wxv = ddx ? wx : 1.f - wx;
                            bool v = yv && ((unsigned)xx < (unsigned)Wn);
                            int xc = min(max(xx, 0), Wn - 1);
                            float wgt = v ? wxv * wyv : 0.f;
                            float val = use_lds ? Plds[(yc - y0b) * PSTR + (xc - x0b)]
                                                : Pb[yc * Wn + xc];
                            acc += val * wgt;
                        }
                    }
                    Rlds[rr * RSTR + rc] = acc;
                }
            }
        }
    }
    __syncthreads();

    // ---- T phase: horizontal bicubic ----
    {
        int oc = tid & 31;
        int rbase = tid >> 5;
        int ox = tx + oc;
        float4 w = g_wt[ox];
        int j0 = g_i0[ox];
        int jc0 = min(max(j0 - 1, 0), CROPD - 1) - jmin;
        int jc1 = min(max(j0 + 0, 0), CROPD - 1) - jmin;
        int jc2 = min(max(j0 + 1, 0), CROPD - 1) - jmin;
        int jc3 = min(max(j0 + 2, 0), CROPD - 1) - jmin;
#pragma unroll
        for (int it = 0; it < 4; it++) {
            int rr = it * 8 + rbase;
            if (rr < nTy) {
                const float* row = &Rlds[rr * RSTR];
                Tlds[rr * RSTR + oc] = w.x * row[jc0] + w.y * row[jc1] +
                                       w.z * row[jc2] + w.w * row[jc3];
            }
        }
    }
    __syncthreads();

    // ---- V phase: 4 outputs/thread, float4 LDS taps + coalesced store ----
    {
        int r = tid >> 3, cg = tid & 7;
        int oy = ty + r, ox0 = tx + cg * 4;
        float4 w = g_wt[oy];
        int i0y = g_i0[oy];
        float wk[4] = {w.x, w.y, w.z, w.w};
        float4 acc = make_float4(0.f, 0.f, 0.f, 0.f);
#pragma unroll
        for (int k = 0; k < 4; k++) {
            int iyc = min(max(i0y - 1 + k, 0), CROPD - 1) - iymin;
            float4 v = *reinterpret_cast<const float4*>(&Tlds[iyc * RSTR + cg * 4]);
            acc.x += wk[k] * v.x;
            acc.y += wk[k] * v.y;
            acc.z += wk[k] * v.z;
            acc.w += wk[k] * v.w;
        }
        *reinterpret_cast<float4*>(out + (size_t)p * PLANE + (size_t)oy * Wn + ox0) = acc;
    }
}

extern "C" void kernel_launch(void* const* d_in, const int* in_sizes, int n_in,
                              void* d_out, int out_size, void* d_ws, size_t ws_size,
                              hipStream_t stream) {
    const float* x          = (const float*)d_in[0];
    const float* noise      = (const float*)d_in[1];
    const float* brightness = (const float*)d_in[2];
    const int*   flip_mask  = (const int*)d_in[3];
    const int*   ep_raw     = (const int*)d_in[4];
    const int*   angles     = (const int*)d_in[5];
    const int*   crop_ij    = (const int*)d_in[6];
    float* out = (float*)d_out;

    float* params = (float*)d_ws;                              // 12 KB
    int4*  pmeta  = (int4*)((char*)d_ws + 16384);              // 12544*16 = 200 KB
    int4*  rmeta  = (int4*)((char*)d_ws + 16384 + 200704);
    float* Pbuf   = (float*)((char*)d_ws + (1 << 20));         // persp out

    params_kernel<<<1, 256, 0, stream>>>(ep_raw, angles, brightness, flip_mask, params);
    meta_kernel<<<49, 256, 0, stream>>>(params, crop_ij, pmeta, rmeta);
    persp_kernel<<<NWG, 256, 0, stream>>>(x, noise, params, pmeta, Pbuf);
    rotresize_kernel<<<NWG, 256, 0, stream>>>(Pbuf, params, crop_ij, rmeta, out);
}

// Round 6
// 270.943 us; speedup vs baseline: 3.4212x; 1.0097x over previous
//
#include <hip/hip_runtime.h>
#include <math.h>

#define Bn 256
#define Cn 3
#define Hn 224
#define Wn 224
#define CROPD 190

static constexpr int PLANE = Hn * Wn;   // 50176

#define TILE 32
// F (source) LDS tile
#define FH 72
#define FSTR 76
// P (perspective result) LDS tile
#define PHR 48
#define PSTR 52
// R/T tiles
#define RSTR 40

#define NWG (768 * 49)     // 37,632
#define CHUNK (NWG / 8)

__device__ int    g_i0[Wn];
__device__ float4 g_wt[Wn];

__device__ __forceinline__ float keys_cubic(float x) {
    if (x < 1.f) return ((1.5f * x - 2.5f) * x) * x + 1.f;
    if (x < 2.f) return ((-0.5f * x + 2.5f) * x - 4.f) * x + 2.f;
    return 0.f;
}
__device__ __forceinline__ float rflf(float v) {
    return __int_as_float(__builtin_amdgcn_readfirstlane(__float_as_int(v)));
}
__device__ __forceinline__ int rfli(int v) { return __builtin_amdgcn_readfirstlane(v); }
__device__ __forceinline__ int swz_block(int bid) {
    return (bid & 7) * CHUNK + (bid >> 3);
}

// params[b*12 + {0..7: homography, 8: cos, 9: sin, 10: brightness, 11: flip}]
__global__ void params_kernel(const int* __restrict__ ep_raw,
                              const int* __restrict__ angles,
                              const float* __restrict__ brightness,
                              const int* __restrict__ flip_mask,
                              float* __restrict__ params) {
    int b = threadIdx.x;

    if (b < Wn) {
        float sf = ((float)b + 0.5f) * ((float)CROPD / (float)Wn) - 0.5f;
        int i0 = (int)floorf(sf);
        float w[4]; float s = 0.f;
#pragma unroll
        for (int k = 0; k < 4; k++) {
            int idx = i0 - 1 + k;
            float wk = (idx >= 0 && idx < CROPD) ? keys_cubic(fabsf(sf - (float)idx)) : 0.f;
            w[k] = wk; s += wk;
        }
        float inv = 1.f / s;
        g_i0[b] = i0;
        g_wt[b] = make_float4(w[0] * inv, w[1] * inv, w[2] * inv, w[3] * inv);
    }

    if (b >= Bn) return;

    const double offx[4] = {0.0, 195.0, 195.0, 0.0};
    const double offy[4] = {0.0, 0.0, 195.0, 195.0};
    const double sxc[4]  = {0.0, 223.0, 223.0, 0.0};
    const double syc[4]  = {0.0, 0.0, 223.0, 223.0};
    double M[8][9];
    for (int i = 0; i < 4; i++) {
        double ex = (double)ep_raw[b * 8 + i * 2 + 0] + offx[i];
        double ey = (double)ep_raw[b * 8 + i * 2 + 1] + offy[i];
        double sx = sxc[i], sy = syc[i];
        M[i][0] = ex; M[i][1] = ey; M[i][2] = 1.0;
        M[i][3] = 0.0; M[i][4] = 0.0; M[i][5] = 0.0;
        M[i][6] = -sx * ex; M[i][7] = -sx * ey; M[i][8] = sx;
        M[i + 4][0] = 0.0; M[i + 4][1] = 0.0; M[i + 4][2] = 0.0;
        M[i + 4][3] = ex; M[i + 4][4] = ey; M[i + 4][5] = 1.0;
        M[i + 4][6] = -sy * ex; M[i + 4][7] = -sy * ey; M[i + 4][8] = sy;
    }
    for (int k = 0; k < 8; k++) {
        int piv = k; double best = fabs(M[k][k]);
        for (int r = k + 1; r < 8; r++) {
            double v = fabs(M[r][k]);
            if (v > best) { best = v; piv = r; }
        }
        if (piv != k)
            for (int j = 0; j < 9; j++) { double tt = M[k][j]; M[k][j] = M[piv][j]; M[piv][j] = tt; }
        double inv = 1.0 / M[k][k];
        for (int r = k + 1; r < 8; r++) {
            double f = M[r][k] * inv;
            M[r][k] = 0.0;
            for (int j = k + 1; j < 9; j++) M[r][j] -= f * M[k][j];
        }
    }
    double sol[8];
    for (int k = 7; k >= 0; k--) {
        double s = M[k][8];
        for (int j = k + 1; j < 8; j++) s -= M[k][j] * sol[j];
        sol[k] = s / M[k][k];
    }
    float* p = params + b * 12;
    for (int j = 0; j < 8; j++) p[j] = (float)sol[j];
    double th = ((double)angles[b] - 16.0) * (M_PI / 180.0);
    p[8]  = (float)cos(th);
    p[9]  = (float)sin(th);
    p[10] = 0.85f + 0.3f * brightness[b];
    p[11] = (flip_mask[b] > 0) ? 1.0f : 0.0f;
}

// Per-(batch,tile): rmeta = P-rect (rot bbox) + rot-interior; smeta = source
// bbox of that P-rect under the perspective map + persp-interior.
__global__ void meta_kernel(const float* __restrict__ params,
                            const int* __restrict__ crop_ij,
                            int4* __restrict__ rmeta,
                            int4* __restrict__ smeta) {
    int bt = blockIdx.x * 256 + threadIdx.x;    // < 12544
    int b = bt / 49, t = bt % 49;
    int ty = (t / 7) * TILE, tx = (t % 7) * TILE;
    const float* prm = params + b * 12;

    // ---- rot bbox over R rect -> P-rect ----
    int x0p, y0p, bwp, bhp;
    {
        float cs = prm[8], sn = prm[9];
        int ci = crop_ij[b * 2 + 0], cj = crop_ij[b * 2 + 1];
        int iymin = max(g_i0[ty] - 1, 0);
        int iymax = min(g_i0[ty + 31] + 2, CROPD - 1);
        int jmin = max(g_i0[tx] - 1, 0);
        int jmax = min(g_i0[tx + 31] + 2, CROPD - 1);
        int ry0 = iymin + ci, ry1 = iymax + ci;
        int rx0 = jmin + cj, rx1 = jmax + cj;
        const float cxc = (Wn - 1) * 0.5f;
        float minrx = 1e30f, maxrx = -1e30f, minry = 1e30f, maxry = -1e30f;
#pragma unroll
        for (int cy = 0; cy < 2; cy++) {
#pragma unroll
            for (int cxr = 0; cxr < 2; cxr++) {
                float dx = (float)(cxr ? rx1 : rx0) - cxc;
                float dy = (float)(cy ? ry1 : ry0) - cxc;
                float rx = cs * dx + sn * dy + cxc;
                float ry = -sn * dx + cs * dy + cxc;
                minrx = fminf(minrx, rx); maxrx = fmaxf(maxrx, rx);
                minry = fminf(minry, ry); maxry = fmaxf(maxry, ry);
            }
        }
        int x0b = min(max((int)floorf(minrx) - 1, 0), Wn - 1);
        int x1b = min(max((int)floorf(maxrx) + 2, 0), Wn - 1);
        int y0b = min(max((int)floorf(minry) - 1, 0), Hn - 1);
        int y1b = min(max((int)floorf(maxry) + 2, 0), Hn - 1);
        x0p = x0b; y0p = y0b;
        bwp = x1b - x0b + 1; bhp = y1b - y0b + 1;
        int inter = (minrx >= 0.5f && maxrx <= 222.0f &&
                     minry >= 0.5f && maxry <= 222.0f) ? 1 : 0;
        rmeta[bt] = make_int4(x0b, y0b, bwp | (inter << 16), bhp);
    }

    // ---- persp source bbox over the P-rect ----
    {
        float a0 = prm[0], a1 = prm[1], a2 = prm[2];
        float a3 = prm[3], a4 = prm[4], a5 = prm[5];
        float g = prm[6], h = prm[7];
        int x1p = x0p + bwp - 1, y1p = y0p + bhp - 1;
        float minsx = 1e30f, maxsx = -1e30f, minsy = 1e30f, maxsy = -1e30f;
#pragma unroll
        for (int cy = 0; cy < 2; cy++) {
#pragma unroll
            for (int cxr = 0; cxr < 2; cxr++) {
                float Xg = (float)(cxr ? x1p : x0p) + 0.5f;
                float Yg = (float)(cy ? y1p : y0p) + 0.5f;
                float rden = 1.0f / (g * Xg + h * Yg + 1.0f);
                float sx = (a0 * Xg + a1 * Yg + a2) * rden - 0.5f;
                float sy = (a3 * Xg + a4 * Yg + a5) * rden - 0.5f;
                minsx = fminf(minsx, sx); maxsx = fmaxf(maxsx, sx);
                minsy = fminf(minsy, sy); maxsy = fmaxf(maxsy, sy);
            }
        }
        int x0s = min(max((int)floorf(minsx) - 1, 0), Wn - 1);
        int x1s = min(max((int)floorf(maxsx) + 2, 0), Wn - 1);
        int y0s = min(max((int)floorf(minsy) - 1, 0), Hn - 1);
        int y1s = min(max((int)floorf(maxsy) + 2, 0), Hn - 1);
        x0s &= ~3;
        int bws = x1s - x0s + 1, bhs = y1s - y0s + 1;
        int inter = (minsx >= 0.5f && maxsx <= 222.0f &&
                     minsy >= 0.5f && maxsy <= 222.0f) ? 1 : 0;
        smeta[bt] = make_int4(x0s, y0s, bws | (inter << 16), bhs);
    }
}

// On-demand perspective sample with global taps (ultra-rare fallback path).
__device__ __forceinline__ float persp_at(const float* __restrict__ xb,
                                          const float* __restrict__ nb,
                                          bool flip, float bf,
                                          float a0, float a1, float a2,
                                          float a3, float a4, float a5,
                                          float g, float h, int ixp, int iyp) {
    float Xg = (float)ixp + 0.5f, Yg = (float)iyp + 0.5f;
    float rden = __builtin_amdgcn_rcpf(g * Xg + h * Yg + 1.0f);
    float sx = (a0 * Xg + a1 * Yg + a2) * rden - 0.5f;
    float sy = (a3 * Xg + a4 * Yg + a5) * rden - 0.5f;
    float fx0 = floorf(sx), fy0 = floorf(sy);
    float wx = sx - fx0, wy = sy - fy0;
    int x0 = (int)fx0, y0 = (int)fy0;
    float acc = 0.f;
#pragma unroll
    for (int dy = 0; dy < 2; dy++) {
        int yy = y0 + dy;
        float wyv = dy ? wy : 1.f - wy;
        bool yv = (unsigned)yy < (unsigned)Hn;
        int yc = min(max(yy, 0), Hn - 1);
#pragma unroll
        for (int dx = 0; dx < 2; dx++) {
            int xx = x0 + dx;
            float wxv = dx ? wx : 1.f - wx;
            bool v = yv && ((unsigned)xx < (unsigned)Wn);
            int xc = min(max(xx, 0), Wn - 1);
            float wgt = v ? wxv * wyv : 0.f;
            int xs = flip ? (Wn - 1 - xc) : xc;
            acc += (xb[yc * Wn + xs] + 0.625f * nb[yc * Wn + xc]) * bf * wgt;
        }
    }
    return acc;
}

// Fully fused: flip+noise+brightness+perspective+rotation+crop+bicubic resize.
// One 32x32 output tile per block.
__global__ __launch_bounds__(256) void mega_kernel(const float* __restrict__ xin,
                                                   const float* __restrict__ noise,
                                                   const float* __restrict__ params,
                                                   const int* __restrict__ crop_ij,
                                                   const int4* __restrict__ rmeta,
                                                   const int4* __restrict__ smeta,
                                                   float* __restrict__ out) {
    // F region (FH*FSTR = 5472 floats) is dead after the P phase; R/T overlay it.
    __shared__ __align__(16) float smem[FH * FSTR + PHR * PSTR];
    float* Flds = smem;                       // 72 x 76
    float* Plds = smem + FH * FSTR;           // 48 x 52
    float* Rlds = smem;                       // 32 x 40 (overlays F)
    float* Tlds = smem + 32 * RSTR;           // 32 x 40

    int bi = swz_block(blockIdx.x);
    int p = bi / 49;
    int t = bi % 49;
    int ty = (t / 7) * TILE;
    int tx = (t % 7) * TILE;
    int b = p / Cn;
    int tid = threadIdx.x;

    int4 rm = rmeta[b * 49 + t];
    int x0p = rm.x, y0p = rm.y;
    int bwp = rm.z & 0xffff;
    bool interior_r = (rm.z >> 16) != 0;
    int bhp = rm.w;
    int4 sm = smeta[b * 49 + t];
    int x0s = sm.x, y0s = sm.y;
    int bws = sm.z & 0xffff;
    bool interior_s = (sm.z >> 16) != 0;
    int bhs = sm.w;
    int y1s = y0s + bhs - 1;
    bool fitF = (bws <= FH) && (bhs <= FH);
    bool fitP = (bwp <= PHR) && (bhp <= PHR);
    bool fast = fitF && fitP;

    const float* prm = params + b * 12;
    float a0 = rflf(prm[0]), a1 = rflf(prm[1]), a2 = rflf(prm[2]);
    float a3 = rflf(prm[3]), a4 = rflf(prm[4]), a5 = rflf(prm[5]);
    float g = rflf(prm[6]), h = rflf(prm[7]), bf = rflf(prm[10]);
    float cs = rflf(prm[8]), sn = rflf(prm[9]);
    bool flip = rflf(prm[11]) > 0.5f;
    int ci = rfli(crop_ij[b * 2 + 0]);
    int cj = rfli(crop_ij[b * 2 + 1]);

    int iymin = max(g_i0[ty] - 1, 0);
    int nTy = min(g_i0[ty + 31] + 2, CROPD - 1) - iymin + 1;
    int jmin = max(g_i0[tx] - 1, 0);
    int nRx = min(g_i0[tx + 31] + 2, CROPD - 1) - jmin + 1;
    int rx0 = jmin + cj, ry0 = iymin + ci;
    const float cxc = (Wn - 1) * 0.5f;

    const size_t base = (size_t)p * PLANE;
    const float* xb = xin + base;
    const float* nb = noise + base;

    // ---- Phase F: stage (flip(x)+0.625*noise)*bf over source bbox ----
    if (fast) {
        int bwq = (bws + 3) >> 2;               // <= 18
        int sh = (bwq <= 8) ? 3 : ((bwq <= 16) ? 4 : 5);
        int c4 = tid & ((1 << sh) - 1);
        int r0 = tid >> sh;
        int rstep = 256 >> sh;
        bool cok = c4 < bwq;
        for (int yy = y0s + r0; yy <= y1s; yy += rstep) {
            if (cok) {
                int xl = min(x0s + c4 * 4, Wn - 4);
                float4 nv = *reinterpret_cast<const float4*>(&nb[yy * Wn + xl]);
                float4 xv;
                if (flip) {
                    float4 xr = *reinterpret_cast<const float4*>(&xb[yy * Wn + (Wn - 4 - xl)]);
                    xv = make_float4(xr.w, xr.z, xr.y, xr.x);
                } else {
                    xv = *reinterpret_cast<const float4*>(&xb[yy * Wn + xl]);
                }
                float4 f = make_float4((xv.x + 0.625f * nv.x) * bf,
                                       (xv.y + 0.625f * nv.y) * bf,
                                       (xv.z + 0.625f * nv.z) * bf,
                                       (xv.w + 0.625f * nv.w) * bf);
                *reinterpret_cast<float4*>(&Flds[(yy - y0s) * FSTR + (xl - x0s)]) = f;
            }
        }
    }
    __syncthreads();

    // ---- Phase P: perspective bilinear into Plds over the P-rect ----
    if (fast) {
        int bwpq = (bwp + 3) >> 2;              // <= 12
        int c4 = tid & 15;
        int r0 = tid >> 4;                      // 16 rows / pass
        bool cok = c4 < bwpq;
        int x1p = x0p + bwp - 1;
        if (interior_s) {
            for (int pr = r0; pr < bhp; pr += 16) {
                if (!cok) continue;
                float Yg = (float)(y0p + pr) + 0.5f;
                float pv[4];
#pragma unroll
                for (int j = 0; j < 4; j++) {
                    int px = min(x0p + c4 * 4 + j, x1p);
                    float Xg = (float)px + 0.5f;
                    float rden = __builtin_amdgcn_rcpf(g * Xg + h * Yg + 1.0f);
                    float sx = (a0 * Xg + a1 * Yg + a2) * rden - 0.5f;
                    float sy = (a3 * Xg + a4 * Yg + a5) * rden - 0.5f;
                    float fx0 = floorf(sx), fy0 = floorf(sy);
                    float wx = sx - fx0, wy = sy - fy0;
                    const float* q = &Flds[((int)fy0 - y0s) * FSTR + ((int)fx0 - x0s)];
                    float top = q[0] + wx * (q[1] - q[0]);
                    float bot = q[FSTR] + wx * (q[FSTR + 1] - q[FSTR]);
                    pv[j] = top + wy * (bot - top);
                }
                *reinterpret_cast<float4*>(&Plds[pr * PSTR + c4 * 4]) =
                    make_float4(pv[0], pv[1], pv[2], pv[3]);
            }
        } else {
            for (int pr = r0; pr < bhp; pr += 16) {
                if (!cok) continue;
                float Yg = (float)(y0p + pr) + 0.5f;
                float pv[4];
#pragma unroll
                for (int j = 0; j < 4; j++) {
                    int px = min(x0p + c4 * 4 + j, x1p);
                    float Xg = (float)px + 0.5f;
                    float rden = __builtin_amdgcn_rcpf(g * Xg + h * Yg + 1.0f);
                    float sx = (a0 * Xg + a1 * Yg + a2) * rden - 0.5f;
                    float sy = (a3 * Xg + a4 * Yg + a5) * rden - 0.5f;
                    float fx0 = floorf(sx), fy0 = floorf(sy);
                    float wx = sx - fx0, wy = sy - fy0;
                    int x0 = (int)fx0, y0 = (int)fy0;
                    float acc = 0.f;
#pragma unroll
                    for (int dy = 0; dy < 2; dy++) {
                        int yy = y0 + dy;
                        float wyv = dy ? wy : 1.f - wy;
                        bool yv = (unsigned)yy < (unsigned)Hn;
                        int yc = min(max(yy, 0), Hn - 1);
#pragma unroll
                        for (int dx = 0; dx < 2; dx++) {
                            int xx = x0 + dx;
                            float wxv = dx ? wx : 1.f - wx;
                            bool v = yv && ((unsigned)xx < (unsigned)Wn);
                            int xc = min(max(xx, 0), Wn - 1);
                            float wgt = v ? wxv * wyv : 0.f;
                            acc += Flds[(yc - y0s) * FSTR + (xc - x0s)] * wgt;
                        }
                    }
                    pv[j] = acc;
                }
                *reinterpret_cast<float4*>(&Plds[pr * PSTR + c4 * 4]) =
                    make_float4(pv[0], pv[1], pv[2], pv[3]);
            }
        }
    }
    __syncthreads();

    // ---- Phase R: rotation bilinear over the R rect (reads Plds) ----
    {
        int rc = tid & 31;
        int rbase = tid >> 5;
        bool cok = rc < nRx;
        float dxc = (float)(rx0 + rc) - cxc;
        float bx = cs * dxc + cxc;
        float by = -sn * dxc + cxc;
        if (fast && interior_r) {
#pragma unroll
            for (int it = 0; it < 4; it++) {
                int rr = it * 8 + rbase;
                if (rr < nTy && cok) {
                    float dyr = (float)(ry0 + rr) - cxc;
                    float srx = bx + sn * dyr;
                    float sry = by + cs * dyr;
                    float fx0 = floorf(srx), fy0 = floorf(sry);
                    float wx = srx - fx0, wy = sry - fy0;
                    const float* q = &Plds[((int)fy0 - y0p) * PSTR + ((int)fx0 - x0p)];
                    float top = q[0] + wx * (q[1] - q[0]);
                    float bot = q[PSTR] + wx * (q[PSTR + 1] - q[PSTR]);
                    Rlds[rr * RSTR + rc] = top + wy * (bot - top);
                }
            }
        } else if (fast) {
#pragma unroll
            for (int it = 0; it < 4; it++) {
                int rr = it * 8 + rbase;
                if (rr < nTy && cok) {
                    float dyr = (float)(ry0 + rr) - cxc;
                    float srx = bx + sn * dyr;
                    float sry = by + cs * dyr;
                    float fx0 = floorf(srx), fy0 = floorf(sry);
                    float wx = srx - fx0, wy = sry - fy0;
                    int x0 = (int)fx0, y0 = (int)fy0;
                    float acc = 0.f;
#pragma unroll
                    for (int ddy = 0; ddy < 2; ddy++) {
                        int yy = y0 + ddy;
                        float wyv = ddy ? wy : 1.f - wy;
                        bool yv = (unsigned)yy < (unsigned)Hn;
                        int yc = min(max(yy, 0), Hn - 1);
#pragma unroll
                        for (int ddx = 0; ddx < 2; ddx++) {
                            int xx = x0 + ddx;
                            float wxv = ddx ? wx : 1.f - wx;
                            bool v = yv && ((unsigned)xx < (unsigned)Wn);
                            int xc = min(max(xx, 0), Wn - 1);
                            float wgt = v ? wxv * wyv : 0.f;
                            acc += Plds[(yc - y0p) * PSTR + (xc - x0p)] * wgt;
                        }
                    }
                    Rlds[rr * RSTR + rc] = acc;
                }
            }
        } else {
            // ultra-rare: compute P on demand with global taps
#pragma unroll
            for (int it = 0; it < 4; it++) {
                int rr = it * 8 + rbase;
                if (rr < nTy && cok) {
                    float dyr = (float)(ry0 + rr) - cxc;
                    float srx = bx + sn * dyr;
                    float sry = by + cs * dyr;
                    float fx0 = floorf(srx), fy0 = floorf(sry);
                    float wx = srx - fx0, wy = sry - fy0;
                    int x0 = (int)fx0, y0 = (int)fy0;
                    float acc = 0.f;
#pragma unroll
                    for (int ddy = 0; ddy < 2; ddy++) {
                        int yy = y0 + ddy;
                        float wyv = ddy ? wy : 1.f - wy;
                        bool yv = (unsigned)yy < (unsigned)Hn;
                        int yc = min(max(yy, 0), Hn - 1);
#pragma unroll
                        for (int ddx = 0; ddx < 2; ddx++) {
                            int xx = x0 + ddx;
                            float wxv = ddx ? wx : 1.f - wx;
                            bool v = yv && ((unsigned)xx < (unsigned)Wn);
                            int xc = min(max(xx, 0), Wn - 1);
                            float wgt = v ? wxv * wyv : 0.f;
                            if (wgt != 0.f)
                                acc += persp_at(xb, nb, flip, bf, a0, a1, a2,
                                                a3, a4, a5, g, h, xc, yc) * wgt;
                        }
                    }
                    Rlds[rr * RSTR + rc] = acc;
                }
            }
        }
    }
    __syncthreads();

    // ---- Phase T: horizontal bicubic ----
    {
        int oc = tid & 31;
        int rbase = tid >> 5;
        int ox = tx + oc;
        float4 w = g_wt[ox];
        int j0 = g_i0[ox];
        int jc0 = min(max(j0 - 1, 0), CROPD - 1) - jmin;
        int jc1 = min(max(j0 + 0, 0), CROPD - 1) - jmin;
        int jc2 = min(max(j0 + 1, 0), CROPD - 1) - jmin;
        int jc3 = min(max(j0 + 2, 0), CROPD - 1) - jmin;
#pragma unroll
        for (int it = 0; it < 4; it++) {
            int rr = it * 8 + rbase;
            if (rr < nTy) {
                const float* row = &Rlds[rr * RSTR];
                Tlds[rr * RSTR + oc] = w.x * row[jc0] + w.y * row[jc1] +
                                       w.z * row[jc2] + w.w * row[jc3];
            }
        }
    }
    __syncthreads();

    // ---- Phase V: vertical bicubic, float4 store ----
    {
        int r = tid >> 3, cg = tid & 7;
        int oy = ty + r, ox0 = tx + cg * 4;
        float4 w = g_wt[oy];
        int i0y = g_i0[oy];
        float wk[4] = {w.x, w.y, w.z, w.w};
        float4 acc = make_float4(0.f, 0.f, 0.f, 0.f);
#pragma unroll
        for (int k = 0; k < 4; k++) {
            int iyc = min(max(i0y - 1 + k, 0), CROPD - 1) - iymin;
            float4 v = *reinterpret_cast<const float4*>(&Tlds[iyc * RSTR + cg * 4]);
            acc.x += wk[k] * v.x;
            acc.y += wk[k] * v.y;
            acc.z += wk[k] * v.z;
            acc.w += wk[k] * v.w;
        }
        *reinterpret_cast<float4*>(out + base + (size_t)oy * Wn + ox0) = acc;
    }
}

extern "C" void kernel_launch(void* const* d_in, const int* in_sizes, int n_in,
                              void* d_out, int out_size, void* d_ws, size_t ws_size,
                              hipStream_t stream) {
    const float* x          = (const float*)d_in[0];
    const float* noise      = (const float*)d_in[1];
    const float* brightness = (const float*)d_in[2];
    const int*   flip_mask  = (const int*)d_in[3];
    const int*   ep_raw     = (const int*)d_in[4];
    const int*   angles     = (const int*)d_in[5];
    const int*   crop_ij    = (const int*)d_in[6];
    float* out = (float*)d_out;

    float* params = (float*)d_ws;                              // 12 KB
    int4*  rmeta  = (int4*)((char*)d_ws + 16384);              // 12544*16
    int4*  smeta  = (int4*)((char*)d_ws + 16384 + 200704);

    params_kernel<<<1, 256, 0, stream>>>(ep_raw, angles, brightness, flip_mask, params);
    meta_kernel<<<49, 256, 0, stream>>>(params, crop_ij, rmeta, smeta);
    mega_kernel<<<NWG, 256, 0, stream>>>(x, noise, params, crop_ij, rmeta, smeta, out);
}